// Round 1
// baseline (1408.121 us; speedup 1.0000x reference)
//
#include <hip/hip_runtime.h>
#include <hip/hip_bf16.h>

// Motion-detection Gauss-LIF SNN, restructured:
//   K1: conv(16x9x9) + LIF1 scan over t  -> spike train Z1 [800][65536] (fp32 0/1)
//   K2: G2 = Z1 @ w1^T  (k-split partials, deterministic)
//   K2b: reduce partials -> G2 [800][200]
//   K3: per-batch sequential LIF2 + FC2 + LIF3 scan -> out [16][50]
//
// Precision: all fp32. LIF recurrences use __fmul_rn/__fadd_rn (no fp-contract)
// to match the reference's mul-then-add rounding. No atomics (bit-stable replays).

#define B_   16
#define T_   50
#define HW_  4096          // 64*64
#define K1N  65536         // 16*64*64 flattened layer-1 size
#define M_   800           // T_*B_
#define N2_  200
#define KSPL 16            // k-splits in K2

// ---------------------------------------------------------------- K1: conv + LIF1
// grid 512 = b(16) x cgroup(8, 2 channels each) x ytile(4, 16 rows each)
// block 256 = (tx 16 x-strips of 4) x (ty 16 rows)
__global__ __launch_bounds__(256) void k1_conv_lif(const float* __restrict__ x,
                                                   const float* __restrict__ kern,
                                                   float* __restrict__ zout){
  const int bid = blockIdx.x;
  const int yt = bid & 3;
  const int cg = (bid >> 2) & 7;
  const int b  = bid >> 5;
  const int tid = threadIdx.x;
  const int tx = tid & 15;
  const int ty = tid >> 4;
  const int y0 = yt * 16;
  const int c0 = cg * 2;

  __shared__ __align__(16) float tile[24][72];   // rows y0-4..y0+19, cols -4..67

  float m1[2][4];
  #pragma unroll
  for (int cl = 0; cl < 2; ++cl)
    #pragma unroll
    for (int xo = 0; xo < 4; ++xo) m1[cl][xo] = 0.f;

  const float* xb = x + (size_t)b * (T_ * HW_);   // x[b][t][0][..]

  for (int t = 0; t < T_; ++t){
    const float* xi = xb + (size_t)t * HW_;
    // stage input tile (zero-padded)
    for (int idx = tid; idx < 24 * 72; idx += 256){
      int r  = idx / 72;
      int cc = idx - r * 72;
      int gy = y0 - 4 + r;
      int gx = cc - 4;
      float v = 0.f;
      if (gy >= 0 && gy < 64 && gx >= 0 && gx < 64) v = xi[gy * 64 + gx];
      tile[r][cc] = v;
    }
    __syncthreads();

    float g[2][4];
    #pragma unroll
    for (int cl = 0; cl < 2; ++cl)
      #pragma unroll
      for (int xo = 0; xo < 4; ++xo) g[cl][xo] = 0.f;

    #pragma unroll
    for (int dy = 0; dy < 9; ++dy){
      const float* trow = &tile[ty + dy][tx * 4];
      float4 a  = *(const float4*)(trow);
      float4 bv = *(const float4*)(trow + 4);
      float4 cv = *(const float4*)(trow + 8);
      float xv[12] = {a.x, a.y, a.z, a.w, bv.x, bv.y, bv.z, bv.w,
                      cv.x, cv.y, cv.z, cv.w};
      #pragma unroll
      for (int cl = 0; cl < 2; ++cl){
        const float* kr = kern + (c0 + cl) * 81 + dy * 9;  // wave-uniform -> s_load
        #pragma unroll
        for (int dx = 0; dx < 9; ++dx){
          float kc = kr[dx];
          #pragma unroll
          for (int xo = 0; xo < 4; ++xo)
            g[cl][xo] = fmaf(kc, xv[dx + xo], g[cl][xo]);
        }
      }
    }

    // LIF1 (reset-to-zero from PREVIOUS membrane) + spike write
    const size_t zb = ((size_t)(t * B_ + b)) * K1N;
    #pragma unroll
    for (int cl = 0; cl < 2; ++cl){
      float4 zv;
      float* zp = (float*)&zv;
      #pragma unroll
      for (int xo = 0; xo < 4; ++xo){
        float m = m1[cl][xo];
        float nm = (m > 1.0f) ? 0.0f : __fadd_rn(__fmul_rn(0.9f, m), g[cl][xo]);
        m1[cl][xo] = nm;
        zp[xo] = (nm > 1.0f) ? 1.0f : 0.0f;
      }
      *(float4*)(zout + zb + (size_t)(c0 + cl) * HW_ + (y0 + ty) * 64 + tx * 4) = zv;
    }
    __syncthreads();
  }
}

// ---------------------------------------------------------------- K2: Z1 @ w1^T (partials)
// grid 512 = m-tile(32, 25 m each) x k-split(16, 4096 k each); block 256 lanes = n
__global__ __launch_bounds__(256) void k2_gemm(const float* __restrict__ z,
                                               const float* __restrict__ w1,
                                               float* __restrict__ P){
  const int bm = blockIdx.x & 31;
  const int ks = blockIdx.x >> 5;
  const int n  = threadIdx.x;
  const int m0 = bm * 25;
  const int k0 = ks * (K1N / KSPL);
  const float* wrow = w1 + (size_t)(n < N2_ ? n : (N2_ - 1)) * K1N;

  float2 acc[25];
  #pragma unroll
  for (int m = 0; m < 25; ++m) acc[m] = make_float2(0.f, 0.f);

  for (int k = k0; k < k0 + (K1N / KSPL); k += 16){
    float4 wa = *(const float4*)(wrow + k);
    float4 wb = *(const float4*)(wrow + k + 4);
    float4 wc = *(const float4*)(wrow + k + 8);
    float4 wd = *(const float4*)(wrow + k + 12);
    float wv[16] = {wa.x, wa.y, wa.z, wa.w, wb.x, wb.y, wb.z, wb.w,
                    wc.x, wc.y, wc.z, wc.w, wd.x, wd.y, wd.z, wd.w};
    #pragma unroll
    for (int m = 0; m < 25; ++m){
      const float* zr = z + (size_t)(m0 + m) * K1N + k;   // wave-uniform -> s_load
      float4 za = *(const float4*)(zr);
      float4 zb = *(const float4*)(zr + 4);
      float4 zc = *(const float4*)(zr + 8);
      float4 zd = *(const float4*)(zr + 12);
      float zv[16] = {za.x, za.y, za.z, za.w, zb.x, zb.y, zb.z, zb.w,
                      zc.x, zc.y, zc.z, zc.w, zd.x, zd.y, zd.z, zd.w};
      float2 a = acc[m];
      #pragma unroll
      for (int kk = 0; kk < 8; ++kk){
        a.x = fmaf(zv[2 * kk],     wv[2 * kk],     a.x);
        a.y = fmaf(zv[2 * kk + 1], wv[2 * kk + 1], a.y);
      }
      acc[m] = a;
    }
  }

  if (n < N2_){
    float* Pp = P + ((size_t)ks * M_ + m0) * N2_ + n;
    #pragma unroll
    for (int m = 0; m < 25; ++m) Pp[(size_t)m * N2_] = acc[m].x + acc[m].y;
  }
}

// ---------------------------------------------------------------- K2b: reduce k-split partials
__global__ __launch_bounds__(256) void k2b_reduce(const float* __restrict__ P,
                                                  float* __restrict__ G2){
  int j = blockIdx.x * 256 + threadIdx.x;
  if (j >= M_ * N2_) return;
  float s = 0.f;
  #pragma unroll
  for (int ks = 0; ks < KSPL; ++ks) s += P[(size_t)ks * (M_ * N2_) + j];
  G2[j] = s;
}

// ---------------------------------------------------------------- K3: LIF2 + FC2 + LIF3 scan
// grid 16 (one block per batch), block 256 (lane = n, active n<200)
__global__ __launch_bounds__(256) void k3_scan(const float* __restrict__ G2,
                                               const float* __restrict__ w2,
                                               float* __restrict__ out){
  const int b = blockIdx.x;
  const int tid = threadIdx.x;
  const float w = (tid < N2_) ? w2[tid] : 0.f;
  float m2 = 0.f, m3 = 0.f;
  __shared__ float part[4];

  float nxt = (tid < N2_) ? G2[(size_t)b * N2_ + tid] : 0.f;
  for (int t = 0; t < T_; ++t){
    float g2v = nxt;
    if (t < T_ - 1 && tid < N2_) nxt = G2[(size_t)((t + 1) * B_ + b) * N2_ + tid];
    float nm = (m2 > 1.0f) ? 0.f : __fadd_rn(__fmul_rn(0.9f, m2), g2v);
    m2 = nm;
    float s = (m2 > 1.0f) ? w : 0.f;
    #pragma unroll
    for (int off = 32; off > 0; off >>= 1) s += __shfl_down(s, off, 64);
    if ((tid & 63) == 0) part[tid >> 6] = s;
    __syncthreads();
    if (tid == 0){
      float g3 = (part[0] + part[1]) + (part[2] + part[3]);
      m3 = __fadd_rn(__fmul_rn(0.95f, m3), g3);
      out[b * T_ + t] = m3;
    }
    __syncthreads();
  }
}

// ---------------------------------------------------------------- host
extern "C" void kernel_launch(void* const* d_in, const int* in_sizes, int n_in,
                              void* d_out, int out_size, void* d_ws, size_t ws_size,
                              hipStream_t stream){
  const float* x    = (const float*)d_in[0];   // [16,50,1,64,64]
  const float* kern = (const float*)d_in[1];   // [16,1,9,9]
  const float* w1   = (const float*)d_in[2];   // [200,65536]
  const float* w2   = (const float*)d_in[3];   // [1,200]
  float* out = (float*)d_out;                  // [16,50,1]

  float* z  = (float*)d_ws;                        // 800*65536 fp32
  float* P  = z + (size_t)M_ * K1N;                // 16*800*200 fp32
  float* G2 = P + (size_t)KSPL * M_ * N2_;         // 800*200 fp32

  size_t need = ((size_t)M_ * K1N + (size_t)KSPL * M_ * N2_ + (size_t)M_ * N2_) * sizeof(float);
  if (ws_size < need) return;  // fail cleanly rather than corrupt

  hipLaunchKernelGGL(k1_conv_lif, dim3(512), dim3(256), 0, stream, x, kern, z);
  hipLaunchKernelGGL(k2_gemm,     dim3(512), dim3(256), 0, stream, z, w1, P);
  hipLaunchKernelGGL(k2b_reduce,  dim3((M_ * N2_ + 255) / 256), dim3(256), 0, stream, P, G2);
  hipLaunchKernelGGL(k3_scan,     dim3(B_), dim3(256), 0, stream, G2, w2, out);
}

// Round 2
// 863.666 us; speedup vs baseline: 1.6304x; 1.6304x over previous
//
#include <hip/hip_runtime.h>
#include <hip/hip_bf16.h>

// Motion-detection Gauss-LIF SNN:
//   K1: conv(16x9x9) + LIF1 scan over t -> spike train Z1 [800][65536] (bf16 0/1, exact)
//   K2: G2 = Z1 @ w1^T  LDS-tiled fp32 GEMM, k-split partials (deterministic order)
//   K2b: reduce partials -> G2 [800][200]
//   K3: per-batch sequential LIF2 + FC2 + LIF3 scan -> out [16][50]
//
// Precision: all math fp32. LIF recurrences use __fmul_rn/__fadd_rn (no contract).
// z is exactly representable in bf16 (0.0/1.0) -> format change is lossless.

#define B_   16
#define T_   50
#define HW_  4096          // 64*64
#define K1N  65536         // 16*64*64 flattened layer-1 size
#define M_   800           // T_*B_
#define N2_  200
#define KSPL 64            // k-splits in K2
#define BM2  32            // K2 m-tile
#define BK2  32            // K2 k-chunk
#define KCH  (K1N / KSPL)  // 1024 k per block
#define MT2  (M_ / BM2)    // 25 m-tiles

// ---------------------------------------------------------------- K1: conv + LIF1
// grid 512 = b(16) x cgroup(8, 2 channels each) x ytile(4, 16 rows each)
// block 256 = (tx 16 x-strips of 4) x (ty 16 rows)
__global__ __launch_bounds__(256) void k1_conv_lif(const float* __restrict__ x,
                                                   const float* __restrict__ kern,
                                                   ushort* __restrict__ zout){
  const int bid = blockIdx.x;
  const int yt = bid & 3;
  const int cg = (bid >> 2) & 7;
  const int b  = bid >> 5;
  const int tid = threadIdx.x;
  const int tx = tid & 15;
  const int ty = tid >> 4;
  const int y0 = yt * 16;
  const int c0 = cg * 2;

  __shared__ __align__(16) float tile[24][72];   // rows y0-4..y0+19, cols -4..67

  float m1[2][4];
  #pragma unroll
  for (int cl = 0; cl < 2; ++cl)
    #pragma unroll
    for (int xo = 0; xo < 4; ++xo) m1[cl][xo] = 0.f;

  const float* xb = x + (size_t)b * (T_ * HW_);

  for (int t = 0; t < T_; ++t){
    const float* xi = xb + (size_t)t * HW_;
    for (int idx = tid; idx < 24 * 72; idx += 256){
      int r  = idx / 72;
      int cc = idx - r * 72;
      int gy = y0 - 4 + r;
      int gx = cc - 4;
      float v = 0.f;
      if (gy >= 0 && gy < 64 && gx >= 0 && gx < 64) v = xi[gy * 64 + gx];
      tile[r][cc] = v;
    }
    __syncthreads();

    float g[2][4];
    #pragma unroll
    for (int cl = 0; cl < 2; ++cl)
      #pragma unroll
      for (int xo = 0; xo < 4; ++xo) g[cl][xo] = 0.f;

    #pragma unroll
    for (int dy = 0; dy < 9; ++dy){
      const float* trow = &tile[ty + dy][tx * 4];
      float4 a  = *(const float4*)(trow);
      float4 bv = *(const float4*)(trow + 4);
      float4 cv = *(const float4*)(trow + 8);
      float xv[12] = {a.x, a.y, a.z, a.w, bv.x, bv.y, bv.z, bv.w,
                      cv.x, cv.y, cv.z, cv.w};
      #pragma unroll
      for (int cl = 0; cl < 2; ++cl){
        const float* kr = kern + (c0 + cl) * 81 + dy * 9;
        #pragma unroll
        for (int dx = 0; dx < 9; ++dx){
          float kc = kr[dx];
          #pragma unroll
          for (int xo = 0; xo < 4; ++xo)
            g[cl][xo] = fmaf(kc, xv[dx + xo], g[cl][xo]);
        }
      }
    }

    // LIF1 (reset-to-zero from PREVIOUS membrane) + bf16 spike write (exact 0/1)
    const size_t zb = ((size_t)(t * B_ + b)) * K1N;
    #pragma unroll
    for (int cl = 0; cl < 2; ++cl){
      ushort4 zv;
      ushort* zp = (ushort*)&zv;
      #pragma unroll
      for (int xo = 0; xo < 4; ++xo){
        float m = m1[cl][xo];
        float nm = (m > 1.0f) ? 0.0f : __fadd_rn(__fmul_rn(0.9f, m), g[cl][xo]);
        m1[cl][xo] = nm;
        zp[xo] = (nm > 1.0f) ? (ushort)0x3F80 : (ushort)0;  // bf16 1.0 / 0.0
      }
      *(ushort4*)(zout + zb + (size_t)(c0 + cl) * HW_ + (y0 + ty) * 64 + tx * 4) = zv;
    }
    __syncthreads();
  }
}

// ---------------------------------------------------------------- K2: Z1 @ w1^T (LDS-tiled)
// grid 1600 = m-tile(25, 32 m) x k-split(64, 1024 k); block 256
// XCD-bijective swizzle: XCD x owns contiguous logical range [x*200, x*200+200)
__global__ __launch_bounds__(256, 4) void k2_gemm(const ushort* __restrict__ z,
                                                  const float* __restrict__ w1,
                                                  float* __restrict__ P){
  const int bid = blockIdx.x;
  const int L = (bid & 7) * (MT2 * KSPL / 8) + (bid >> 3);  // 1600/8 = 200 per XCD
  const int ks = L / MT2;
  const int mt = L % MT2;
  const int m0 = mt * BM2;
  const int k0 = ks * KCH;

  __shared__ float wt[256][33];   // n rows (200 real, 56 zero), stride 33: conflict-free
  __shared__ float zt[BM2][33];

  const int t  = threadIdx.x;
  const int tn = t & 63;          // n = tn + 64*jj
  const int tm = t >> 6;          // m = tm*8 + i  (uniform per wave -> LDS broadcast)

  float acc[8][4];
  #pragma unroll
  for (int i = 0; i < 8; ++i)
    #pragma unroll
    for (int jj = 0; jj < 4; ++jj) acc[i][jj] = 0.f;

  for (int kc = 0; kc < KCH; kc += BK2){
    // stage w-tile: 256 n x 32 k (float4 coalesced, zeros for n>=200)
    #pragma unroll
    for (int i = 0; i < 8; ++i){
      int idx = t + 256 * i;            // 0..2047 float4 slots
      int n   = idx >> 3;
      int k4  = (idx & 7) * 4;
      float4 v = make_float4(0.f, 0.f, 0.f, 0.f);
      if (n < N2_) v = *(const float4*)(w1 + (size_t)n * K1N + k0 + kc + k4);
      wt[n][k4] = v.x; wt[n][k4 + 1] = v.y; wt[n][k4 + 2] = v.z; wt[n][k4 + 3] = v.w;
    }
    // stage z-tile: 32 m x 32 k (bf16 -> fp32, exact)
    #pragma unroll
    for (int i = 0; i < 4; ++i){
      int idx = t + 256 * i;            // 0..1023
      int m   = idx >> 5;
      int kk  = idx & 31;
      ushort uz = z[(size_t)(m0 + m) * K1N + k0 + kc + kk];
      zt[m][kk] = __uint_as_float(((unsigned)uz) << 16);
    }
    __syncthreads();

    #pragma unroll 8
    for (int kk = 0; kk < BK2; ++kk){
      float wv[4], zv[8];
      #pragma unroll
      for (int jj = 0; jj < 4; ++jj) wv[jj] = wt[tn + 64 * jj][kk];
      #pragma unroll
      for (int i = 0; i < 8; ++i) zv[i] = zt[tm * 8 + i][kk];
      #pragma unroll
      for (int i = 0; i < 8; ++i)
        #pragma unroll
        for (int jj = 0; jj < 4; ++jj)
          acc[i][jj] = fmaf(zv[i], wv[jj], acc[i][jj]);
    }
    __syncthreads();
  }

  #pragma unroll
  for (int i = 0; i < 8; ++i){
    int m = m0 + tm * 8 + i;
    #pragma unroll
    for (int jj = 0; jj < 4; ++jj){
      int n = tn + 64 * jj;
      if (n < N2_) P[((size_t)ks * M_ + m) * N2_ + n] = acc[i][jj];
    }
  }
}

// ---------------------------------------------------------------- K2b: reduce k-split partials
__global__ __launch_bounds__(256) void k2b_reduce(const float* __restrict__ P,
                                                  float* __restrict__ G2){
  int j = blockIdx.x * 256 + threadIdx.x;
  if (j >= M_ * N2_) return;
  float s = 0.f;
  #pragma unroll
  for (int ks = 0; ks < KSPL; ++ks) s += P[(size_t)ks * (M_ * N2_) + j];
  G2[j] = s;
}

// ---------------------------------------------------------------- K3: LIF2 + FC2 + LIF3 scan
__global__ __launch_bounds__(256) void k3_scan(const float* __restrict__ G2,
                                               const float* __restrict__ w2,
                                               float* __restrict__ out){
  const int b = blockIdx.x;
  const int tid = threadIdx.x;
  const float w = (tid < N2_) ? w2[tid] : 0.f;
  float m2 = 0.f, m3 = 0.f;
  __shared__ float part[4];

  float nxt = (tid < N2_) ? G2[(size_t)b * N2_ + tid] : 0.f;
  for (int t = 0; t < T_; ++t){
    float g2v = nxt;
    if (t < T_ - 1 && tid < N2_) nxt = G2[(size_t)((t + 1) * B_ + b) * N2_ + tid];
    float nm = (m2 > 1.0f) ? 0.f : __fadd_rn(__fmul_rn(0.9f, m2), g2v);
    m2 = nm;
    float s = (m2 > 1.0f) ? w : 0.f;
    #pragma unroll
    for (int off = 32; off > 0; off >>= 1) s += __shfl_down(s, off, 64);
    if ((tid & 63) == 0) part[tid >> 6] = s;
    __syncthreads();
    if (tid == 0){
      float g3 = (part[0] + part[1]) + (part[2] + part[3]);
      m3 = __fadd_rn(__fmul_rn(0.95f, m3), g3);
      out[b * T_ + t] = m3;
    }
    __syncthreads();
  }
}

// ---------------------------------------------------------------- host
extern "C" void kernel_launch(void* const* d_in, const int* in_sizes, int n_in,
                              void* d_out, int out_size, void* d_ws, size_t ws_size,
                              hipStream_t stream){
  const float* x    = (const float*)d_in[0];   // [16,50,1,64,64]
  const float* kern = (const float*)d_in[1];   // [16,1,9,9]
  const float* w1   = (const float*)d_in[2];   // [200,65536]
  const float* w2   = (const float*)d_in[3];   // [1,200]
  float* out = (float*)d_out;                  // [16,50,1]

  ushort* zb16 = (ushort*)d_ws;                                // 800*65536 bf16
  float*  P    = (float*)((char*)d_ws + (size_t)M_ * K1N * 2); // KSPL*800*200 fp32
  float*  G2   = P + (size_t)KSPL * M_ * N2_;                  // 800*200 fp32

  size_t need = (size_t)M_ * K1N * 2 +
                ((size_t)KSPL * M_ * N2_ + (size_t)M_ * N2_) * sizeof(float);
  if (ws_size < need) return;

  hipLaunchKernelGGL(k1_conv_lif, dim3(512), dim3(256), 0, stream, x, kern, zb16);
  hipLaunchKernelGGL(k2_gemm,     dim3(MT2 * KSPL), dim3(256), 0, stream, zb16, w1, P);
  hipLaunchKernelGGL(k2b_reduce,  dim3((M_ * N2_ + 255) / 256), dim3(256), 0, stream, P, G2);
  hipLaunchKernelGGL(k3_scan,     dim3(B_), dim3(256), 0, stream, G2, w2, out);
}

// Round 3
// 526.313 us; speedup vs baseline: 2.6754x; 1.6410x over previous
//
#include <hip/hip_runtime.h>
#include <hip/hip_bf16.h>

// Motion-detection Gauss-LIF SNN:
//   K0: w1 -> (wh, wl) bf16 hi/lo split (exact to 2^-17 rel; z in {0,1} makes
//       z*wh, z*wl products EXACT, so G2 error ~1e-6 abs worst case)
//   K1: conv(9x9, 1 ch/block, taps in VGPRs) + LIF1 scan -> Z1 [800][65536] bf16 0/1
//   K2: G2 = Z1 @ (wh+wl)^T via MFMA bf16 16x16x32, hi+lo folded into same acc
//       (fixed program order, deterministic), k-split partials
//   K2b: reduce partials -> G2 [800][200]
//   K3: sequential LIF2 + FC2 + LIF3 scan -> out [16][50]
// All accumulation fp32; LIF recurrences __fmul_rn/__fadd_rn (no contract).

typedef __attribute__((ext_vector_type(8))) short short8;
typedef __attribute__((ext_vector_type(4))) float f32x4;

#define B_   16
#define T_   50
#define HW_  4096
#define K1N  65536
#define M_   800
#define N2_  200
#define NP_  256           // padded N rows in wh/wl
#define KSPL 64
#define BM2  128
#define BK2  32
#define KCH  (K1N / KSPL)  // 1024
#define MT2  7             // ceil(800/128)

// ---------------------------------------------------------------- K0: w1 -> bf16 hi/lo
__global__ __launch_bounds__(256) void k0_split(const float* __restrict__ w1,
                                                ushort* __restrict__ wh,
                                                ushort* __restrict__ wl){
  const int TOT = NP_ * K1N / 4;                 // float4-granular slots
  for (int j = blockIdx.x * 256 + threadIdx.x; j < TOT; j += gridDim.x * 256){
    int n = j >> 14;                             // 16384 f4 per row
    int k = (j & 16383) * 4;
    ushort4 h = make_ushort4(0, 0, 0, 0);
    ushort4 lo = make_ushort4(0, 0, 0, 0);
    if (n < N2_){
      float4 v = *(const float4*)(w1 + (size_t)n * K1N + k);
      float vv[4] = {v.x, v.y, v.z, v.w};
      ushort hb[4], lb[4];
      #pragma unroll
      for (int i = 0; i < 4; ++i){
        __hip_bfloat16 hx = __float2bfloat16(vv[i]);
        float hf = __bfloat162float(hx);
        __hip_bfloat16 lx = __float2bfloat16(vv[i] - hf);
        hb[i] = *reinterpret_cast<ushort*>(&hx);
        lb[i] = *reinterpret_cast<ushort*>(&lx);
      }
      h  = make_ushort4(hb[0], hb[1], hb[2], hb[3]);
      lo = make_ushort4(lb[0], lb[1], lb[2], lb[3]);
    }
    *(ushort4*)(wh + (size_t)n * K1N + k) = h;
    *(ushort4*)(wl + (size_t)n * K1N + k) = lo;
  }
}

// ---------------------------------------------------------------- K1: conv + LIF1
// grid 512 = b(16) x c(16) x ytile(2 of 32 rows); block 256 = ty(32) x txg(8 of 8px)
__global__ __launch_bounds__(256) void k1_conv_lif(const float* __restrict__ x,
                                                   const float* __restrict__ kern,
                                                   ushort* __restrict__ zout){
  const int bid = blockIdx.x;
  const int yt = bid & 1;
  const int c  = (bid >> 1) & 15;
  const int b  = bid >> 5;
  const int tid = threadIdx.x;
  const int txg = tid & 7;
  const int ty  = tid >> 3;
  const int y0  = yt * 32;

  __shared__ __align__(16) float tile[40 * 76];  // rows y0-4..y0+35, cols -4..67, stride 76

  float kv[81];
  #pragma unroll
  for (int i = 0; i < 81; ++i) kv[i] = kern[c * 81 + i];   // hoisted: VGPR-resident taps

  float m1[8];
  #pragma unroll
  for (int xo = 0; xo < 8; ++xo) m1[xo] = 0.f;

  const float* xb = x + (size_t)b * (T_ * HW_);

  for (int t = 0; t < T_; ++t){
    const float* xi = xb + (size_t)t * HW_;
    for (int idx = tid; idx < 40 * 72; idx += 256){
      int r  = idx / 72;
      int cc = idx - r * 72;
      int gy = y0 - 4 + r;
      int gx = cc - 4;
      float v = 0.f;
      if (gy >= 0 && gy < 64 && gx >= 0 && gx < 64) v = xi[gy * 64 + gx];
      tile[r * 76 + cc] = v;
    }
    __syncthreads();

    float g[8];
    #pragma unroll
    for (int xo = 0; xo < 8; ++xo) g[xo] = 0.f;

    #pragma unroll
    for (int dy = 0; dy < 9; ++dy){
      const float* base = tile + (ty + dy) * 76 + txg * 8;
      float4 w0 = *(const float4*)(base);
      float4 w1v = *(const float4*)(base + 4);
      float4 w2v = *(const float4*)(base + 8);
      float4 w3v = *(const float4*)(base + 12);
      float xv[16] = {w0.x, w0.y, w0.z, w0.w, w1v.x, w1v.y, w1v.z, w1v.w,
                      w2v.x, w2v.y, w2v.z, w2v.w, w3v.x, w3v.y, w3v.z, w3v.w};
      #pragma unroll
      for (int dx = 0; dx < 9; ++dx){
        float tap = kv[dy * 9 + dx];
        #pragma unroll
        for (int xo = 0; xo < 8; ++xo)
          g[xo] = fmaf(tap, xv[dx + xo], g[xo]);
      }
    }

    // LIF1 (reset-to-zero from previous membrane) + bf16 spike write (exact 0/1)
    ushort zs[8];
    #pragma unroll
    for (int xo = 0; xo < 8; ++xo){
      float m = m1[xo];
      float nm = (m > 1.0f) ? 0.0f : __fadd_rn(__fmul_rn(0.9f, m), g[xo]);
      m1[xo] = nm;
      zs[xo] = (nm > 1.0f) ? (ushort)0x3F80 : (ushort)0;
    }
    uint4 zw = make_uint4((uint)zs[0] | ((uint)zs[1] << 16),
                          (uint)zs[2] | ((uint)zs[3] << 16),
                          (uint)zs[4] | ((uint)zs[5] << 16),
                          (uint)zs[6] | ((uint)zs[7] << 16));
    *(uint4*)(zout + ((size_t)(t * B_ + b)) * K1N + (size_t)c * HW_ +
              (y0 + ty) * 64 + txg * 8) = zw;
    __syncthreads();
  }
}

// ---------------------------------------------------------------- K2: MFMA GEMM
// grid 448 = m-tile(7 x 128) x k-split(64 x 1024); block 256 = 4 waves, each wave
// owns all 128 m x 64 n. XCD-chunked swizzle: XCD x gets ks range [8x, 8x+8).
__global__ __launch_bounds__(256, 2) void k2_gemm(const ushort* __restrict__ z,
                                                  const ushort* __restrict__ wh,
                                                  const ushort* __restrict__ wl,
                                                  float* __restrict__ P){
  __shared__ __align__(16) ushort Al[128 * 40];   // 128 m rows, 32 k + pad(8), 80B stride
  __shared__ __align__(16) ushort Bw[512 * 40];   // hi rows 0-255, lo rows 256-511

  const int bid = blockIdx.x;
  const int L = (bid & 7) * 56 + (bid >> 3);      // bijective: 448 = 8 * 56
  const int ks = L / MT2;
  const int mt = L % MT2;
  const int m0 = mt * BM2;
  const int k0 = ks * KCH;
  const int t  = threadIdx.x;
  const int w  = t >> 6;
  const int l  = t & 63;
  const int lr = l & 15;
  const int lq = l >> 4;

  f32x4 acc[8][4];
  #pragma unroll
  for (int mf = 0; mf < 8; ++mf)
    #pragma unroll
    for (int nf = 0; nf < 4; ++nf) acc[mf][nf] = (f32x4)(0.f);

  #pragma unroll 1
  for (int kc = 0; kc < KCH; kc += BK2){
    const int kg = k0 + kc;
    // stage A tile: 128 m x 32 k bf16 (zeros for m >= 800)
    #pragma unroll
    for (int i = 0; i < 2; ++i){
      int idx = t + 256 * i;
      int row = idx >> 2, c16 = idx & 3;
      int m = m0 + row;
      uint4 v = make_uint4(0, 0, 0, 0);
      if (m < M_) v = *(const uint4*)(z + (size_t)m * K1N + kg + c16 * 8);
      *(uint4*)(Al + row * 40 + c16 * 8) = v;
    }
    // stage B tile: wh 256 x 32 + wl 256 x 32
    #pragma unroll
    for (int i = 0; i < 8; ++i){
      int idx = t + 256 * i;
      int sel = idx >> 10;
      int r   = (idx >> 2) & 255;
      int c16 = idx & 3;
      const ushort* src = sel ? wl : wh;
      uint4 v = *(const uint4*)(src + (size_t)r * K1N + kg + c16 * 8);
      *(uint4*)(Bw + (sel * 256 + r) * 40 + c16 * 8) = v;
    }
    __syncthreads();

    short8 af[8], bh[4], bl[4];
    #pragma unroll
    for (int mf = 0; mf < 8; ++mf)
      af[mf] = *(const short8*)(Al + (mf * 16 + lr) * 40 + lq * 8);
    #pragma unroll
    for (int nf = 0; nf < 4; ++nf){
      bh[nf] = *(const short8*)(Bw + (w * 64 + nf * 16 + lr) * 40 + lq * 8);
      bl[nf] = *(const short8*)(Bw + (256 + w * 64 + nf * 16 + lr) * 40 + lq * 8);
    }
    #pragma unroll
    for (int mf = 0; mf < 8; ++mf)
      #pragma unroll
      for (int nf = 0; nf < 4; ++nf){
        acc[mf][nf] = __builtin_amdgcn_mfma_f32_16x16x32_bf16(af[mf], bh[nf], acc[mf][nf], 0, 0, 0);
        acc[mf][nf] = __builtin_amdgcn_mfma_f32_16x16x32_bf16(af[mf], bl[nf], acc[mf][nf], 0, 0, 0);
      }
    __syncthreads();
  }

  // epilogue: C/D layout col = lane&15, row = (lane>>4)*4 + reg  [m89-verified]
  #pragma unroll
  for (int mf = 0; mf < 8; ++mf)
    #pragma unroll
    for (int nf = 0; nf < 4; ++nf)
      #pragma unroll
      for (int r = 0; r < 4; ++r){
        int m = m0 + mf * 16 + lq * 4 + r;
        int n = w * 64 + nf * 16 + lr;
        if (m < M_ && n < N2_)
          P[((size_t)ks * M_ + m) * N2_ + n] = acc[mf][nf][r];
      }
}

// ---------------------------------------------------------------- K2b: reduce k-splits
__global__ __launch_bounds__(256) void k2b_reduce(const float* __restrict__ P,
                                                  float* __restrict__ G2){
  int j = blockIdx.x * 256 + threadIdx.x;
  if (j >= M_ * N2_) return;
  float s = 0.f;
  #pragma unroll
  for (int ks = 0; ks < KSPL; ++ks) s += P[(size_t)ks * (M_ * N2_) + j];
  G2[j] = s;
}

// ---------------------------------------------------------------- K3: LIF2+FC2+LIF3 scan
__global__ __launch_bounds__(256) void k3_scan(const float* __restrict__ G2,
                                               const float* __restrict__ w2,
                                               float* __restrict__ out){
  const int b = blockIdx.x;
  const int tid = threadIdx.x;
  const float w = (tid < N2_) ? w2[tid] : 0.f;
  float m2 = 0.f, m3 = 0.f;
  __shared__ float part[4];

  float nxt = (tid < N2_) ? G2[(size_t)b * N2_ + tid] : 0.f;
  for (int t = 0; t < T_; ++t){
    float g2v = nxt;
    if (t < T_ - 1 && tid < N2_) nxt = G2[(size_t)((t + 1) * B_ + b) * N2_ + tid];
    float nm = (m2 > 1.0f) ? 0.f : __fadd_rn(__fmul_rn(0.9f, m2), g2v);
    m2 = nm;
    float s = (m2 > 1.0f) ? w : 0.f;
    #pragma unroll
    for (int off = 32; off > 0; off >>= 1) s += __shfl_down(s, off, 64);
    if ((tid & 63) == 0) part[tid >> 6] = s;
    __syncthreads();
    if (tid == 0){
      float g3 = (part[0] + part[1]) + (part[2] + part[3]);
      m3 = __fadd_rn(__fmul_rn(0.95f, m3), g3);
      out[b * T_ + t] = m3;
    }
    __syncthreads();
  }
}

// ---------------------------------------------------------------- host
extern "C" void kernel_launch(void* const* d_in, const int* in_sizes, int n_in,
                              void* d_out, int out_size, void* d_ws, size_t ws_size,
                              hipStream_t stream){
  const float* x    = (const float*)d_in[0];   // [16,50,1,64,64]
  const float* kern = (const float*)d_in[1];   // [16,1,9,9]
  const float* w1   = (const float*)d_in[2];   // [200,65536]
  const float* w2   = (const float*)d_in[3];   // [1,200]
  float* out = (float*)d_out;                  // [16,50,1]

  char* p = (char*)d_ws;
  ushort* zb16 = (ushort*)p;                 p += (size_t)M_ * K1N * 2;        // 104.86 MB
  ushort* wh   = (ushort*)p;                 p += (size_t)NP_ * K1N * 2;       // 33.55 MB
  ushort* wl   = (ushort*)p;                 p += (size_t)NP_ * K1N * 2;       // 33.55 MB
  float*  P    = (float*)p;                  p += (size_t)KSPL * M_ * N2_ * 4; // 40.96 MB
  float*  G2   = (float*)p;                  p += (size_t)M_ * N2_ * 4;        // 0.64 MB

  size_t need = (size_t)(p - (char*)d_ws);
  if (ws_size < need) return;

  hipLaunchKernelGGL(k0_split,    dim3(4096), dim3(256), 0, stream, w1, wh, wl);
  hipLaunchKernelGGL(k1_conv_lif, dim3(512),  dim3(256), 0, stream, x, kern, zb16);
  hipLaunchKernelGGL(k2_gemm,     dim3(MT2 * KSPL), dim3(256), 0, stream, zb16, wh, wl, P);
  hipLaunchKernelGGL(k2b_reduce,  dim3((M_ * N2_ + 255) / 256), dim3(256), 0, stream, P, G2);
  hipLaunchKernelGGL(k3_scan,     dim3(B_), dim3(256), 0, stream, G2, w2, out);
}

// Round 4
// 241.276 us; speedup vs baseline: 5.8362x; 2.1814x over previous
//
#include <hip/hip_runtime.h>
#include <hip/hip_bf16.h>

// Motion-detection Gauss-LIF SNN:
//   K0: w1 -> bf16 hi/lo split, columns PERMUTED to k' (the order K1's MFMA
//       epilogue writes z in). GEMM is invariant to a shared k-permutation.
//   K1: conv(16x9x9) via MFMA bf16 16x16x32 (taps=A 16ch rows, x-windows=B),
//       x split xh+xm+xl (3x bf16 ~ 24-bit exact), taps kh+kl (2^-17, the
//       same split K2 already uses on w1 -> proven error band). 4 terms:
//       hh + mh + lh + hl. LIF1 in registers across t. z written coalesced
//       in k'-order.
//   K2: G2 = Z1 @ (wh+wl)^T MFMA GEMM, k-split partials (unchanged, passing)
//   K2b: reduce partials; K3: sequential LIF2+FC2+LIF3 scan.
// LIF recurrences use __fmul_rn/__fadd_rn (no contract). Deterministic.

typedef __attribute__((ext_vector_type(8))) short short8;
typedef __attribute__((ext_vector_type(4))) float f32x4;

#define B_   16
#define T_   50
#define HW_  4096
#define K1N  65536
#define M_   800
#define N2_  200
#define NP_  256
#define KSPL 64
#define BM2  128
#define BK2  32
#define KCH  (K1N / KSPL)  // 1024
#define MT2  7             // ceil(800/128)

static __device__ __forceinline__ short8 mk8(uint a, uint b, uint c, uint d){
  union { uint u[4]; short8 v; } x;
  x.u[0] = a; x.u[1] = b; x.u[2] = c; x.u[3] = d;
  return x.v;
}

// ---------------------------------------------------------------- K0: permute + bf16 split
// k' = strip*2048 + o*256 + s*16 + q*4 + r  <->  orig k = ch*4096 + py*64 + col
//   ch = 4q + r, p128 = 8s + o, py = 2*strip + (p128>>6), col = p128 & 63
// block = (n, strip): reads 16 runs of 128 consecutive floats (coalesced).
__global__ __launch_bounds__(256) void k0_perm(const float* __restrict__ w1,
                                               ushort* __restrict__ wh,
                                               ushort* __restrict__ wl){
  __shared__ ushort lh[2048], ll[2048];
  const int n = blockIdx.x >> 5;
  const int strip = blockIdx.x & 31;
  const int tid = threadIdx.x;
  #pragma unroll
  for (int i = 0; i < 8; ++i){
    int lin = tid + 256 * i;               // ch*128 + p128
    int ch = lin >> 7, p128 = lin & 127;
    float v = w1[(size_t)n * K1N + ch * 4096 + strip * 128 + p128];
    int s = p128 >> 3, o = p128 & 7, q = ch >> 2, r = ch & 3;
    int kp = o * 256 + s * 16 + q * 4 + r;
    __hip_bfloat16 h = __float2bfloat16(v);
    float hf = __bfloat162float(h);
    __hip_bfloat16 lo = __float2bfloat16(v - hf);
    lh[kp] = *reinterpret_cast<ushort*>(&h);
    ll[kp] = *reinterpret_cast<ushort*>(&lo);
  }
  __syncthreads();
  const size_t ob = (size_t)n * K1N + strip * 2048;
  #pragma unroll
  for (int i = 0; i < 2; ++i){
    int j = (tid + 256 * i) * 4;
    *(ushort4*)(wh + ob + j) = make_ushort4(lh[j], lh[j+1], lh[j+2], lh[j+3]);
    *(ushort4*)(wl + ob + j) = make_ushort4(ll[j], ll[j+1], ll[j+2], ll[j+3]);
  }
}

// ---------------------------------------------------------------- K1: MFMA conv + LIF1
// grid 512 = b(16) x strip(32, 2 image rows each); block 256 = 4 waves.
// Wave w handles px-offsets o in {2w, 2w+1}. Lane: q=l>>4, s=l&15.
// Output frag: row(ch) = 4q+reg, col(px-slot) = s, pixel p128 = 8s+o.
// K-layout: k = dy*16 + dx (dy<10, dx<16; taps zero-padded). kstep ks covers
// dy {2ks, 2ks+1}; quadrant q -> dy = 2ks + (q>>1), dx0 = (q&1)*8.
__global__ __launch_bounds__(256) void k1_conv_mfma(const float* __restrict__ x,
                                                    const float* __restrict__ kern,
                                                    ushort* __restrict__ zout){
  const int strip = blockIdx.x & 31;
  const int b = blockIdx.x >> 5;
  const int tid = threadIdx.x;
  const int w = tid >> 6;
  const int l = tid & 63;
  const int q = l >> 4;
  const int s = l & 15;

  __shared__ ushort Ah[16 * 160 + 8];      // taps hi (bf16 bits), row stride 160
  __shared__ ushort Alo[16 * 160 + 8];     // taps lo
  __shared__ ushort Th[12 * 82 + 8];       // x hi, 12 rows x 82 (80 data + 2 pad)
  __shared__ ushort Tm[12 * 82 + 8];       // x mid
  __shared__ ushort Tl[12 * 82 + 8];       // x lo

  // ---- taps: kh + kl bf16 split, zero-padded to 10x16
  for (int slot = tid; slot < 16 * 160; slot += 256){
    int ch = slot / 160, kk = slot - ch * 160;
    int dy = kk >> 4, dx = kk & 15;
    float v = 0.f;
    if (dy < 9 && dx < 9) v = kern[ch * 81 + dy * 9 + dx];
    __hip_bfloat16 h = __float2bfloat16(v);
    float hf = __bfloat162float(h);
    __hip_bfloat16 lo = __float2bfloat16(v - hf);
    Ah[slot]  = *reinterpret_cast<ushort*>(&h);
    Alo[slot] = *reinterpret_cast<ushort*>(&lo);
  }
  __syncthreads();

  // ---- preload A-fragments (lane&15 = ch row), 5 ksteps x {h,l}
  short8 afh[5], afl[5];
  #pragma unroll
  for (int ks = 0; ks < 5; ++ks){
    afh[ks] = *(const short8*)(Ah + s * 160 + ks * 32 + q * 8);
    afl[ks] = *(const short8*)(Alo + s * 160 + ks * 32 + q * 8);
  }

  // ---- per-lane aligned B-window base (elements); wave-uniform o handled by
  //      reading 5 dwords and static 16-bit funnel shifts.
  const int p0   = (s >> 3) + (q >> 1);
  const int dx0  = (q & 1) * 8;
  const int bbyte = (p0 * 82 + 8 * (s & 7) + dx0 + 2 * w) * 2;  // + ks*328

  float m1v[2][4];
  #pragma unroll
  for (int oi = 0; oi < 2; ++oi)
    #pragma unroll
    for (int r = 0; r < 4; ++r) m1v[oi][r] = 0.f;

  const float* xb = x + (size_t)b * (T_ * HW_);
  const int r0 = 2 * strip - 4;

  for (int t = 0; t < T_; ++t){
    // ---- stage 12 rows x 80 cols as xh/xm/xl bf16 (zero halo)
    const float* xi = xb + (size_t)t * HW_;
    if (tid < 240){
      int r = tid / 20, c4 = tid - r * 20;
      int imr = r0 + r;
      float vv[4] = {0.f, 0.f, 0.f, 0.f};
      if (imr >= 0 && imr < 64 && c4 >= 1 && c4 <= 16){
        float4 f = *(const float4*)(xi + imr * 64 + (c4 - 1) * 4);
        vv[0] = f.x; vv[1] = f.y; vv[2] = f.z; vv[3] = f.w;
      }
      ushort sh[4], sm[4], sl[4];
      #pragma unroll
      for (int ii = 0; ii < 4; ++ii){
        __hip_bfloat16 h = __float2bfloat16(vv[ii]);
        float t1 = vv[ii] - __bfloat162float(h);
        __hip_bfloat16 m = __float2bfloat16(t1);
        float t2 = t1 - __bfloat162float(m);
        __hip_bfloat16 lo = __float2bfloat16(t2);
        sh[ii] = *reinterpret_cast<ushort*>(&h);
        sm[ii] = *reinterpret_cast<ushort*>(&m);
        sl[ii] = *reinterpret_cast<ushort*>(&lo);
      }
      int eb = r * 82 + c4 * 4;
      *(ushort2*)(Th + eb)     = make_ushort2(sh[0], sh[1]);
      *(ushort2*)(Th + eb + 2) = make_ushort2(sh[2], sh[3]);
      *(ushort2*)(Tm + eb)     = make_ushort2(sm[0], sm[1]);
      *(ushort2*)(Tm + eb + 2) = make_ushort2(sm[2], sm[3]);
      *(ushort2*)(Tl + eb)     = make_ushort2(sl[0], sl[1]);
      *(ushort2*)(Tl + eb + 2) = make_ushort2(sl[2], sl[3]);
    }
    __syncthreads();

    // ---- 4-term MFMA accumulation for o = 2w (acc0) and 2w+1 (acc1)
    f32x4 acc0 = (f32x4)(0.f), acc1 = (f32x4)(0.f);
    #pragma unroll
    for (int ks = 0; ks < 5; ++ks){
      const char* ph = (const char*)Th + bbyte + ks * 328;
      const char* pm = (const char*)Tm + bbyte + ks * 328;
      const char* pl = (const char*)Tl + bbyte + ks * 328;
      uint dh[5], dm[5], dl[5];
      #pragma unroll
      for (int k2 = 0; k2 < 5; ++k2){
        dh[k2] = *(const uint*)(ph + 4 * k2);
        dm[k2] = *(const uint*)(pm + 4 * k2);
        dl[k2] = *(const uint*)(pl + 4 * k2);
      }
      short8 bh0 = mk8(dh[0], dh[1], dh[2], dh[3]);
      short8 bm0 = mk8(dm[0], dm[1], dm[2], dm[3]);
      short8 bl0 = mk8(dl[0], dl[1], dl[2], dl[3]);
      acc0 = __builtin_amdgcn_mfma_f32_16x16x32_bf16(afh[ks], bh0, acc0, 0, 0, 0);
      acc0 = __builtin_amdgcn_mfma_f32_16x16x32_bf16(afh[ks], bm0, acc0, 0, 0, 0);
      acc0 = __builtin_amdgcn_mfma_f32_16x16x32_bf16(afh[ks], bl0, acc0, 0, 0, 0);
      acc0 = __builtin_amdgcn_mfma_f32_16x16x32_bf16(afl[ks], bh0, acc0, 0, 0, 0);
      short8 bh1 = mk8((dh[0] >> 16) | (dh[1] << 16), (dh[1] >> 16) | (dh[2] << 16),
                       (dh[2] >> 16) | (dh[3] << 16), (dh[3] >> 16) | (dh[4] << 16));
      short8 bm1 = mk8((dm[0] >> 16) | (dm[1] << 16), (dm[1] >> 16) | (dm[2] << 16),
                       (dm[2] >> 16) | (dm[3] << 16), (dm[3] >> 16) | (dm[4] << 16));
      short8 bl1 = mk8((dl[0] >> 16) | (dl[1] << 16), (dl[1] >> 16) | (dl[2] << 16),
                       (dl[2] >> 16) | (dl[3] << 16), (dl[3] >> 16) | (dl[4] << 16));
      acc1 = __builtin_amdgcn_mfma_f32_16x16x32_bf16(afh[ks], bh1, acc1, 0, 0, 0);
      acc1 = __builtin_amdgcn_mfma_f32_16x16x32_bf16(afh[ks], bm1, acc1, 0, 0, 0);
      acc1 = __builtin_amdgcn_mfma_f32_16x16x32_bf16(afh[ks], bl1, acc1, 0, 0, 0);
      acc1 = __builtin_amdgcn_mfma_f32_16x16x32_bf16(afl[ks], bh1, acc1, 0, 0, 0);
    }

    // ---- LIF1 + coalesced z store in k'-order
    const size_t zr = ((size_t)(t * B_ + b)) * K1N + strip * 2048 + s * 16 + q * 4;
    {
      ushort4 zv; ushort* zp = (ushort*)&zv;
      #pragma unroll
      for (int r = 0; r < 4; ++r){
        float m = m1v[0][r];
        float nm = (m > 1.0f) ? 0.0f : __fadd_rn(__fmul_rn(0.9f, m), acc0[r]);
        m1v[0][r] = nm;
        zp[r] = (nm > 1.0f) ? (ushort)0x3F80 : (ushort)0;
      }
      *(ushort4*)(zout + zr + (size_t)(2 * w) * 256) = zv;
    }
    {
      ushort4 zv; ushort* zp = (ushort*)&zv;
      #pragma unroll
      for (int r = 0; r < 4; ++r){
        float m = m1v[1][r];
        float nm = (m > 1.0f) ? 0.0f : __fadd_rn(__fmul_rn(0.9f, m), acc1[r]);
        m1v[1][r] = nm;
        zp[r] = (nm > 1.0f) ? (ushort)0x3F80 : (ushort)0;
      }
      *(ushort4*)(zout + zr + (size_t)(2 * w + 1) * 256) = zv;
    }
    __syncthreads();
  }
}

// ---------------------------------------------------------------- K2: MFMA GEMM (unchanged)
__global__ __launch_bounds__(256, 2) void k2_gemm(const ushort* __restrict__ z,
                                                  const ushort* __restrict__ wh,
                                                  const ushort* __restrict__ wl,
                                                  float* __restrict__ P){
  __shared__ __align__(16) ushort Al[128 * 40];
  __shared__ __align__(16) ushort Bw[512 * 40];

  const int bid = blockIdx.x;
  const int L = (bid & 7) * 56 + (bid >> 3);
  const int ks = L / MT2;
  const int mt = L % MT2;
  const int m0 = mt * BM2;
  const int k0 = ks * KCH;
  const int t  = threadIdx.x;
  const int w  = t >> 6;
  const int l  = t & 63;
  const int lr = l & 15;
  const int lq = l >> 4;

  f32x4 acc[8][4];
  #pragma unroll
  for (int mf = 0; mf < 8; ++mf)
    #pragma unroll
    for (int nf = 0; nf < 4; ++nf) acc[mf][nf] = (f32x4)(0.f);

  #pragma unroll 1
  for (int kc = 0; kc < KCH; kc += BK2){
    const int kg = k0 + kc;
    #pragma unroll
    for (int i = 0; i < 2; ++i){
      int idx = t + 256 * i;
      int row = idx >> 2, c16 = idx & 3;
      int m = m0 + row;
      uint4 v = make_uint4(0, 0, 0, 0);
      if (m < M_) v = *(const uint4*)(z + (size_t)m * K1N + kg + c16 * 8);
      *(uint4*)(Al + row * 40 + c16 * 8) = v;
    }
    #pragma unroll
    for (int i = 0; i < 8; ++i){
      int idx = t + 256 * i;
      int sel = idx >> 10;
      int r   = (idx >> 2) & 255;
      int c16 = idx & 3;
      const ushort* src = sel ? wl : wh;
      uint4 v = *(const uint4*)(src + (size_t)r * K1N + kg + c16 * 8);
      *(uint4*)(Bw + (sel * 256 + r) * 40 + c16 * 8) = v;
    }
    __syncthreads();

    short8 af[8], bh[4], bl[4];
    #pragma unroll
    for (int mf = 0; mf < 8; ++mf)
      af[mf] = *(const short8*)(Al + (mf * 16 + lr) * 40 + lq * 8);
    #pragma unroll
    for (int nf = 0; nf < 4; ++nf){
      bh[nf] = *(const short8*)(Bw + (w * 64 + nf * 16 + lr) * 40 + lq * 8);
      bl[nf] = *(const short8*)(Bw + (256 + w * 64 + nf * 16 + lr) * 40 + lq * 8);
    }
    #pragma unroll
    for (int mf = 0; mf < 8; ++mf)
      #pragma unroll
      for (int nf = 0; nf < 4; ++nf){
        acc[mf][nf] = __builtin_amdgcn_mfma_f32_16x16x32_bf16(af[mf], bh[nf], acc[mf][nf], 0, 0, 0);
        acc[mf][nf] = __builtin_amdgcn_mfma_f32_16x16x32_bf16(af[mf], bl[nf], acc[mf][nf], 0, 0, 0);
      }
    __syncthreads();
  }

  #pragma unroll
  for (int mf = 0; mf < 8; ++mf)
    #pragma unroll
    for (int nf = 0; nf < 4; ++nf)
      #pragma unroll
      for (int r = 0; r < 4; ++r){
        int m = m0 + mf * 16 + lq * 4 + r;
        int n = w * 64 + nf * 16 + lr;
        if (m < M_ && n < N2_)
          P[((size_t)ks * M_ + m) * N2_ + n] = acc[mf][nf][r];
      }
}

// ---------------------------------------------------------------- K2b: reduce k-splits
__global__ __launch_bounds__(256) void k2b_reduce(const float* __restrict__ P,
                                                  float* __restrict__ G2){
  int j = blockIdx.x * 256 + threadIdx.x;
  if (j >= M_ * N2_) return;
  float s = 0.f;
  #pragma unroll
  for (int ks = 0; ks < KSPL; ++ks) s += P[(size_t)ks * (M_ * N2_) + j];
  G2[j] = s;
}

// ---------------------------------------------------------------- K3: LIF2+FC2+LIF3 scan
__global__ __launch_bounds__(256) void k3_scan(const float* __restrict__ G2,
                                               const float* __restrict__ w2,
                                               float* __restrict__ out){
  const int b = blockIdx.x;
  const int tid = threadIdx.x;
  const float w = (tid < N2_) ? w2[tid] : 0.f;
  float m2 = 0.f, m3 = 0.f;
  __shared__ float part[4];

  float nxt = (tid < N2_) ? G2[(size_t)b * N2_ + tid] : 0.f;
  for (int t = 0; t < T_; ++t){
    float g2v = nxt;
    if (t < T_ - 1 && tid < N2_) nxt = G2[(size_t)((t + 1) * B_ + b) * N2_ + tid];
    float nm = (m2 > 1.0f) ? 0.f : __fadd_rn(__fmul_rn(0.9f, m2), g2v);
    m2 = nm;
    float s = (m2 > 1.0f) ? w : 0.f;
    #pragma unroll
    for (int off = 32; off > 0; off >>= 1) s += __shfl_down(s, off, 64);
    if ((tid & 63) == 0) part[tid >> 6] = s;
    __syncthreads();
    if (tid == 0){
      float g3 = (part[0] + part[1]) + (part[2] + part[3]);
      m3 = __fadd_rn(__fmul_rn(0.95f, m3), g3);
      out[b * T_ + t] = m3;
    }
    __syncthreads();
  }
}

// ---------------------------------------------------------------- host
extern "C" void kernel_launch(void* const* d_in, const int* in_sizes, int n_in,
                              void* d_out, int out_size, void* d_ws, size_t ws_size,
                              hipStream_t stream){
  const float* x    = (const float*)d_in[0];
  const float* kern = (const float*)d_in[1];
  const float* w1   = (const float*)d_in[2];
  const float* w2   = (const float*)d_in[3];
  float* out = (float*)d_out;

  char* p = (char*)d_ws;
  ushort* zb16 = (ushort*)p;                 p += (size_t)M_ * K1N * 2;
  ushort* wh   = (ushort*)p;                 p += (size_t)NP_ * K1N * 2;
  ushort* wl   = (ushort*)p;                 p += (size_t)NP_ * K1N * 2;
  float*  P    = (float*)p;                  p += (size_t)KSPL * M_ * N2_ * 4;
  float*  G2   = (float*)p;                  p += (size_t)M_ * N2_ * 4;

  size_t need = (size_t)(p - (char*)d_ws);
  if (ws_size < need) return;

  hipLaunchKernelGGL(k0_perm,      dim3(200 * 32), dim3(256), 0, stream, w1, wh, wl);
  hipLaunchKernelGGL(k1_conv_mfma, dim3(512),      dim3(256), 0, stream, x, kern, zb16);
  hipLaunchKernelGGL(k2_gemm,      dim3(MT2 * KSPL), dim3(256), 0, stream, zb16, wh, wl, P);
  hipLaunchKernelGGL(k2b_reduce,   dim3((M_ * N2_ + 255) / 256), dim3(256), 0, stream, P, G2);
  hipLaunchKernelGGL(k3_scan,      dim3(B_), dim3(256), 0, stream, G2, w2, out);
}

// Round 5
// 205.522 us; speedup vs baseline: 6.8514x; 1.1740x over previous
//
#include <hip/hip_runtime.h>
#include <hip/hip_bf16.h>

// Motion-detection Gauss-LIF SNN:
//   K0: w1 -> bf16 hi/lo split, columns permuted to k' (K1's z write order).
//   K1: conv(16x9x9) via MFMA bf16 16x16x32; x = xh+xm+xl (exact), taps kh+kl
//       (2^-17). Double-buffered x tiles, 1 barrier/t, prefetched staging,
//       b64-based window reads (wave-uniform alignment via stride 84).
//   K2: G2 = Z1 @ (wh+wl)^T MFMA GEMM, k-split partials, register prefetch.
//   K2b: reduce partials; K3: sequential LIF2+FC2+LIF3 scan.
// LIF recurrences __fmul_rn/__fadd_rn (no contract). Deterministic order.

typedef __attribute__((ext_vector_type(8))) short short8;
typedef __attribute__((ext_vector_type(4))) float f32x4;

#define B_   16
#define T_   50
#define HW_  4096
#define K1N  65536
#define M_   800
#define N2_  200
#define NP_  256
#define KSPL 64
#define BM2  128
#define BK2  32
#define KCH  (K1N / KSPL)  // 1024
#define MT2  7             // ceil(800/128)
#define SW   84            // k1 tile stride (168B: 8B-aligned rows)

static __device__ __forceinline__ short8 mk8(uint a, uint b, uint c, uint d){
  union { uint u[4]; short8 v; } x;
  x.u[0] = a; x.u[1] = b; x.u[2] = c; x.u[3] = d;
  return x.v;
}
static __device__ __forceinline__ uint fnl(uint a, uint b){ return (a >> 16) | (b << 16); }

// ---------------------------------------------------------------- K0: permute + bf16 split
__global__ __launch_bounds__(256) void k0_perm(const float* __restrict__ w1,
                                               ushort* __restrict__ wh,
                                               ushort* __restrict__ wl){
  __shared__ ushort lh[2048], ll[2048];
  const int n = blockIdx.x >> 5;
  const int strip = blockIdx.x & 31;
  const int tid = threadIdx.x;
  #pragma unroll
  for (int i = 0; i < 8; ++i){
    int lin = tid + 256 * i;               // ch*128 + p128
    int ch = lin >> 7, p128 = lin & 127;
    float v = w1[(size_t)n * K1N + ch * 4096 + strip * 128 + p128];
    int s = p128 >> 3, o = p128 & 7, q = ch >> 2, r = ch & 3;
    int kp = o * 256 + s * 16 + q * 4 + r;
    __hip_bfloat16 h = __float2bfloat16(v);
    float hf = __bfloat162float(h);
    __hip_bfloat16 lo = __float2bfloat16(v - hf);
    lh[kp] = *reinterpret_cast<ushort*>(&h);
    ll[kp] = *reinterpret_cast<ushort*>(&lo);
  }
  __syncthreads();
  const size_t ob = (size_t)n * K1N + strip * 2048;
  #pragma unroll
  for (int i = 0; i < 2; ++i){
    int j = (tid + 256 * i) * 4;
    *(ushort4*)(wh + ob + j) = make_ushort4(lh[j], lh[j+1], lh[j+2], lh[j+3]);
    *(ushort4*)(wl + ob + j) = make_ushort4(ll[j], ll[j+1], ll[j+2], ll[j+3]);
  }
}

// ---------------------------------------------------------------- K1 helpers
template<bool WODD>
static __device__ __forceinline__ void rd5(const uint* p, int dw, uint e[5]){
  if (WODD){
    e[0] = p[dw];
    uint2 a = *(const uint2*)(p + dw + 1);
    uint2 b = *(const uint2*)(p + dw + 3);
    e[1] = a.x; e[2] = a.y; e[3] = b.x; e[4] = b.y;
  } else {
    uint2 a = *(const uint2*)(p + dw);
    uint2 b = *(const uint2*)(p + dw + 2);
    e[0] = a.x; e[1] = a.y; e[2] = b.x; e[3] = b.y;
    e[4] = p[dw + 4];
  }
}

template<bool WODD>
static __device__ __forceinline__ void conv_phase(const uint* T0, const uint* T1,
                                                  const uint* T2, int bdw,
                                                  const short8 (&afh)[5],
                                                  const short8 (&afl)[5],
                                                  f32x4& acc0, f32x4& acc1){
  #pragma unroll
  for (int ks = 0; ks < 5; ++ks){
    const int dw = bdw + (SW / 2) * 2 * ks;   // +84 dwords per kstep (2 rows)
    uint h[5], m[5], l[5];
    rd5<WODD>(T0, dw, h);
    rd5<WODD>(T1, dw, m);
    rd5<WODD>(T2, dw, l);
    short8 bh0 = mk8(h[0], h[1], h[2], h[3]);
    short8 bm0 = mk8(m[0], m[1], m[2], m[3]);
    short8 bl0 = mk8(l[0], l[1], l[2], l[3]);
    acc0 = __builtin_amdgcn_mfma_f32_16x16x32_bf16(afh[ks], bh0, acc0, 0, 0, 0);
    acc0 = __builtin_amdgcn_mfma_f32_16x16x32_bf16(afh[ks], bm0, acc0, 0, 0, 0);
    acc0 = __builtin_amdgcn_mfma_f32_16x16x32_bf16(afh[ks], bl0, acc0, 0, 0, 0);
    acc0 = __builtin_amdgcn_mfma_f32_16x16x32_bf16(afl[ks], bh0, acc0, 0, 0, 0);
    short8 bh1 = mk8(fnl(h[0], h[1]), fnl(h[1], h[2]), fnl(h[2], h[3]), fnl(h[3], h[4]));
    short8 bm1 = mk8(fnl(m[0], m[1]), fnl(m[1], m[2]), fnl(m[2], m[3]), fnl(m[3], m[4]));
    short8 bl1 = mk8(fnl(l[0], l[1]), fnl(l[1], l[2]), fnl(l[2], l[3]), fnl(l[3], l[4]));
    acc1 = __builtin_amdgcn_mfma_f32_16x16x32_bf16(afh[ks], bh1, acc1, 0, 0, 0);
    acc1 = __builtin_amdgcn_mfma_f32_16x16x32_bf16(afh[ks], bm1, acc1, 0, 0, 0);
    acc1 = __builtin_amdgcn_mfma_f32_16x16x32_bf16(afh[ks], bl1, acc1, 0, 0, 0);
    acc1 = __builtin_amdgcn_mfma_f32_16x16x32_bf16(afl[ks], bh1, acc1, 0, 0, 0);
  }
}

// ---------------------------------------------------------------- K1: MFMA conv + LIF1
// grid 512 = b(16) x strip(32); block 256 = 4 waves; wave w -> offsets {2w,2w+1}
__global__ __launch_bounds__(256) void k1_conv_mfma(const float* __restrict__ x,
                                                    const float* __restrict__ kern,
                                                    ushort* __restrict__ zout){
  const int strip = blockIdx.x & 31;
  const int b = blockIdx.x >> 5;
  const int tid = threadIdx.x;
  const int w = tid >> 6;
  const int l = tid & 63;
  const int q = l >> 4;
  const int s = l & 15;

  __shared__ __align__(16) ushort Ah[16 * 160];
  __shared__ __align__(16) ushort Alo[16 * 160];
  __shared__ __align__(16) ushort Tt[2][3][12 * SW];   // dbuf x {h,m,l} x tile

  // ---- taps: kh + kl bf16 split, zero-padded to 10x16
  for (int slot = tid; slot < 16 * 160; slot += 256){
    int ch = slot / 160, kk = slot - ch * 160;
    int dy = kk >> 4, dx = kk & 15;
    float v = 0.f;
    if (dy < 9 && dx < 9) v = kern[ch * 81 + dy * 9 + dx];
    __hip_bfloat16 h = __float2bfloat16(v);
    float hf = __bfloat162float(h);
    __hip_bfloat16 lo = __float2bfloat16(v - hf);
    Ah[slot]  = *reinterpret_cast<ushort*>(&h);
    Alo[slot] = *reinterpret_cast<ushort*>(&lo);
  }

  // ---- staging geometry (threads 0..239)
  const bool sact = tid < 240;
  const int sr = tid / 20, sc4 = tid - sr * 20;
  const int r0 = 2 * strip - 4;
  const int imr = r0 + sr;
  const bool sin = sact && imr >= 0 && imr < 64 && sc4 >= 1 && sc4 <= 16;
  const float* xb = x + (size_t)b * (T_ * HW_);
  const float* xsrc = xb + (sin ? (imr * 64 + (sc4 - 1) * 4) : 0);

  // stage t=0 tile
  {
    float4 f0 = make_float4(0.f, 0.f, 0.f, 0.f);
    if (sin) f0 = *(const float4*)(xsrc);
    if (sact){
      float vv[4] = {f0.x, f0.y, f0.z, f0.w};
      ushort sh[4], sm[4], sl[4];
      #pragma unroll
      for (int ii = 0; ii < 4; ++ii){
        __hip_bfloat16 h = __float2bfloat16(vv[ii]);
        float t1 = vv[ii] - __bfloat162float(h);
        __hip_bfloat16 m = __float2bfloat16(t1);
        float t2 = t1 - __bfloat162float(m);
        __hip_bfloat16 lo = __float2bfloat16(t2);
        sh[ii] = *reinterpret_cast<ushort*>(&h);
        sm[ii] = *reinterpret_cast<ushort*>(&m);
        sl[ii] = *reinterpret_cast<ushort*>(&lo);
      }
      int eb = sr * SW + sc4 * 4;
      *(ushort4*)(&Tt[0][0][eb]) = make_ushort4(sh[0], sh[1], sh[2], sh[3]);
      *(ushort4*)(&Tt[0][1][eb]) = make_ushort4(sm[0], sm[1], sm[2], sm[3]);
      *(ushort4*)(&Tt[0][2][eb]) = make_ushort4(sl[0], sl[1], sl[2], sl[3]);
    }
  }
  __syncthreads();

  // ---- preload A-fragments
  short8 afh[5], afl[5];
  #pragma unroll
  for (int ks = 0; ks < 5; ++ks){
    afh[ks] = *(const short8*)(Ah + s * 160 + ks * 32 + q * 8);
    afl[ks] = *(const short8*)(Alo + s * 160 + ks * 32 + q * 8);
  }

  // window base in dwords: 42*p0 + 4*(s&7) + 4*(q&1) + w  (parity == w&1)
  const int p0 = (s >> 3) + (q >> 1);
  const int bdw = 42 * p0 + 4 * (s & 7) + 4 * (q & 1) + w;
  const bool wodd = (w & 1) != 0;

  float m1v[2][4];
  #pragma unroll
  for (int oi = 0; oi < 2; ++oi)
    #pragma unroll
    for (int r = 0; r < 4; ++r) m1v[oi][r] = 0.f;

  for (int t = 0; t < T_; ++t){
    __syncthreads();                           // Tt[t&1] ready
    // prefetch next-t pixels (consumed at end of this iteration)
    float4 nfx = make_float4(0.f, 0.f, 0.f, 0.f);
    if (t + 1 < T_ && sin) nfx = *(const float4*)(xsrc + (size_t)(t + 1) * HW_);

    const int bb = t & 1;
    const uint* T0 = (const uint*)Tt[bb][0];
    const uint* T1 = (const uint*)Tt[bb][1];
    const uint* T2 = (const uint*)Tt[bb][2];
    f32x4 acc0 = (f32x4)(0.f), acc1 = (f32x4)(0.f);
    if (wodd) conv_phase<true >(T0, T1, T2, bdw, afh, afl, acc0, acc1);
    else      conv_phase<false>(T0, T1, T2, bdw, afh, afl, acc0, acc1);

    // ---- LIF1 + coalesced z store in k'-order
    const size_t zr = ((size_t)(t * B_ + b)) * K1N + strip * 2048 + s * 16 + q * 4;
    {
      ushort4 zv; ushort* zp = (ushort*)&zv;
      #pragma unroll
      for (int r = 0; r < 4; ++r){
        float m = m1v[0][r];
        float nm = (m > 1.0f) ? 0.0f : __fadd_rn(__fmul_rn(0.9f, m), acc0[r]);
        m1v[0][r] = nm;
        zp[r] = (nm > 1.0f) ? (ushort)0x3F80 : (ushort)0;
      }
      *(ushort4*)(zout + zr + (size_t)(2 * w) * 256) = zv;
    }
    {
      ushort4 zv; ushort* zp = (ushort*)&zv;
      #pragma unroll
      for (int r = 0; r < 4; ++r){
        float m = m1v[1][r];
        float nm = (m > 1.0f) ? 0.0f : __fadd_rn(__fmul_rn(0.9f, m), acc1[r]);
        m1v[1][r] = nm;
        zp[r] = (nm > 1.0f) ? (ushort)0x3F80 : (ushort)0;
      }
      *(ushort4*)(zout + zr + (size_t)(2 * w + 1) * 256) = zv;
    }

    // ---- stage next tile into the other buffer (readers of it finished pre-barrier)
    if (t + 1 < T_ && sact){
      float vv[4] = {nfx.x, nfx.y, nfx.z, nfx.w};
      ushort sh[4], sm[4], sl[4];
      #pragma unroll
      for (int ii = 0; ii < 4; ++ii){
        __hip_bfloat16 h = __float2bfloat16(vv[ii]);
        float t1 = vv[ii] - __bfloat162float(h);
        __hip_bfloat16 m = __float2bfloat16(t1);
        float t2 = t1 - __bfloat162float(m);
        __hip_bfloat16 lo = __float2bfloat16(t2);
        sh[ii] = *reinterpret_cast<ushort*>(&h);
        sm[ii] = *reinterpret_cast<ushort*>(&m);
        sl[ii] = *reinterpret_cast<ushort*>(&lo);
      }
      int eb = sr * SW + sc4 * 4;
      *(ushort4*)(&Tt[bb ^ 1][0][eb]) = make_ushort4(sh[0], sh[1], sh[2], sh[3]);
      *(ushort4*)(&Tt[bb ^ 1][1][eb]) = make_ushort4(sm[0], sm[1], sm[2], sm[3]);
      *(ushort4*)(&Tt[bb ^ 1][2][eb]) = make_ushort4(sl[0], sl[1], sl[2], sl[3]);
    }
  }
}

// ---------------------------------------------------------------- K2 prefetch loader
static __device__ __forceinline__ void k2_load(const ushort* __restrict__ z,
                                               const ushort* __restrict__ wh,
                                               const ushort* __restrict__ wl,
                                               int m0, int kg, int tid,
                                               uint4 pa[2], uint4 pb[8]){
  #pragma unroll
  for (int i = 0; i < 2; ++i){
    int idx = tid + 256 * i;
    int row = idx >> 2, c16 = idx & 3;
    int m = m0 + row;
    pa[i] = make_uint4(0, 0, 0, 0);
    if (m < M_) pa[i] = *(const uint4*)(z + (size_t)m * K1N + kg + c16 * 8);
  }
  #pragma unroll
  for (int i = 0; i < 8; ++i){
    int idx = tid + 256 * i;
    int sel = idx >> 10;
    int r   = (idx >> 2) & 255;
    int c16 = idx & 3;
    const ushort* src = sel ? wl : wh;
    pb[i] = make_uint4(0, 0, 0, 0);
    if (r < N2_) pb[i] = *(const uint4*)(src + (size_t)r * K1N + kg + c16 * 8);
  }
}

// ---------------------------------------------------------------- K2: MFMA GEMM + prefetch
__global__ __launch_bounds__(256, 2) void k2_gemm(const ushort* __restrict__ z,
                                                  const ushort* __restrict__ wh,
                                                  const ushort* __restrict__ wl,
                                                  float* __restrict__ P){
  __shared__ __align__(16) ushort Al[128 * 40];
  __shared__ __align__(16) ushort Bw[512 * 40];

  const int bid = blockIdx.x;
  const int L = (bid & 7) * 56 + (bid >> 3);      // bijective: 448 = 8 * 56
  const int ks = L / MT2;
  const int mt = L % MT2;
  const int m0 = mt * BM2;
  const int k0 = ks * KCH;
  const int tid = threadIdx.x;
  const int w  = tid >> 6;
  const int l  = tid & 63;
  const int lr = l & 15;
  const int lq = l >> 4;

  f32x4 acc[8][4];
  #pragma unroll
  for (int mf = 0; mf < 8; ++mf)
    #pragma unroll
    for (int nf = 0; nf < 4; ++nf) acc[mf][nf] = (f32x4)(0.f);

  uint4 pa[2], pb[8];
  k2_load(z, wh, wl, m0, k0, tid, pa, pb);

  #pragma unroll 1
  for (int kc = 0; kc < KCH; kc += BK2){
    // write prefetched tile to LDS
    #pragma unroll
    for (int i = 0; i < 2; ++i){
      int idx = tid + 256 * i;
      int row = idx >> 2, c16 = idx & 3;
      *(uint4*)(Al + row * 40 + c16 * 8) = pa[i];
    }
    #pragma unroll
    for (int i = 0; i < 8; ++i){
      int idx = tid + 256 * i;
      int sel = idx >> 10;
      int r   = (idx >> 2) & 255;
      int c16 = idx & 3;
      *(uint4*)(Bw + (sel * 256 + r) * 40 + c16 * 8) = pb[i];
    }
    __syncthreads();

    // issue next tile's global loads (hidden under MFMA phase)
    if (kc + BK2 < KCH) k2_load(z, wh, wl, m0, k0 + kc + BK2, tid, pa, pb);

    short8 af[8], bh[4], bl[4];
    #pragma unroll
    for (int mf = 0; mf < 8; ++mf)
      af[mf] = *(const short8*)(Al + (mf * 16 + lr) * 40 + lq * 8);
    #pragma unroll
    for (int nf = 0; nf < 4; ++nf){
      bh[nf] = *(const short8*)(Bw + (w * 64 + nf * 16 + lr) * 40 + lq * 8);
      bl[nf] = *(const short8*)(Bw + (256 + w * 64 + nf * 16 + lr) * 40 + lq * 8);
    }
    #pragma unroll
    for (int mf = 0; mf < 8; ++mf)
      #pragma unroll
      for (int nf = 0; nf < 4; ++nf){
        acc[mf][nf] = __builtin_amdgcn_mfma_f32_16x16x32_bf16(af[mf], bh[nf], acc[mf][nf], 0, 0, 0);
        acc[mf][nf] = __builtin_amdgcn_mfma_f32_16x16x32_bf16(af[mf], bl[nf], acc[mf][nf], 0, 0, 0);
      }
    __syncthreads();
  }

  #pragma unroll
  for (int mf = 0; mf < 8; ++mf)
    #pragma unroll
    for (int nf = 0; nf < 4; ++nf)
      #pragma unroll
      for (int r = 0; r < 4; ++r){
        int m = m0 + mf * 16 + lq * 4 + r;
        int n = w * 64 + nf * 16 + lr;
        if (m < M_ && n < N2_)
          P[((size_t)ks * M_ + m) * N2_ + n] = acc[mf][nf][r];
      }
}

// ---------------------------------------------------------------- K2b: reduce k-splits
__global__ __launch_bounds__(256) void k2b_reduce(const float* __restrict__ P,
                                                  float* __restrict__ G2){
  int j = blockIdx.x * 256 + threadIdx.x;
  if (j >= M_ * N2_) return;
  float s = 0.f;
  #pragma unroll
  for (int ks = 0; ks < KSPL; ++ks) s += P[(size_t)ks * (M_ * N2_) + j];
  G2[j] = s;
}

// ---------------------------------------------------------------- K3: LIF2+FC2+LIF3 scan
__global__ __launch_bounds__(256) void k3_scan(const float* __restrict__ G2,
                                               const float* __restrict__ w2,
                                               float* __restrict__ out){
  const int b = blockIdx.x;
  const int tid = threadIdx.x;
  const float w = (tid < N2_) ? w2[tid] : 0.f;
  float m2 = 0.f, m3 = 0.f;
  __shared__ float part[4];

  float nxt = (tid < N2_) ? G2[(size_t)b * N2_ + tid] : 0.f;
  for (int t = 0; t < T_; ++t){
    float g2v = nxt;
    if (t < T_ - 1 && tid < N2_) nxt = G2[(size_t)((t + 1) * B_ + b) * N2_ + tid];
    float nm = (m2 > 1.0f) ? 0.f : __fadd_rn(__fmul_rn(0.9f, m2), g2v);
    m2 = nm;
    float s = (m2 > 1.0f) ? w : 0.f;
    #pragma unroll
    for (int off = 32; off > 0; off >>= 1) s += __shfl_down(s, off, 64);
    if ((tid & 63) == 0) part[tid >> 6] = s;
    __syncthreads();
    if (tid == 0){
      float g3 = (part[0] + part[1]) + (part[2] + part[3]);
      m3 = __fadd_rn(__fmul_rn(0.95f, m3), g3);
      out[b * T_ + t] = m3;
    }
    __syncthreads();
  }
}

// ---------------------------------------------------------------- host
extern "C" void kernel_launch(void* const* d_in, const int* in_sizes, int n_in,
                              void* d_out, int out_size, void* d_ws, size_t ws_size,
                              hipStream_t stream){
  const float* x    = (const float*)d_in[0];
  const float* kern = (const float*)d_in[1];
  const float* w1   = (const float*)d_in[2];
  const float* w2   = (const float*)d_in[3];
  float* out = (float*)d_out;

  char* p = (char*)d_ws;
  ushort* zb16 = (ushort*)p;                 p += (size_t)M_ * K1N * 2;
  ushort* wh   = (ushort*)p;                 p += (size_t)NP_ * K1N * 2;
  ushort* wl   = (ushort*)p;                 p += (size_t)NP_ * K1N * 2;
  float*  P    = (float*)p;                  p += (size_t)KSPL * M_ * N2_ * 4;
  float*  G2   = (float*)p;                  p += (size_t)M_ * N2_ * 4;

  size_t need = (size_t)(p - (char*)d_ws);
  if (ws_size < need) return;

  hipLaunchKernelGGL(k0_perm,      dim3(200 * 32), dim3(256), 0, stream, w1, wh, wl);
  hipLaunchKernelGGL(k1_conv_mfma, dim3(512),      dim3(256), 0, stream, x, kern, zb16);
  hipLaunchKernelGGL(k2_gemm,      dim3(MT2 * KSPL), dim3(256), 0, stream, zb16, wh, wl, P);
  hipLaunchKernelGGL(k2b_reduce,   dim3((M_ * N2_ + 255) / 256), dim3(256), 0, stream, P, G2);
  hipLaunchKernelGGL(k3_scan,      dim3(B_), dim3(256), 0, stream, G2, w2, out);
}

// Round 6
// 179.057 us; speedup vs baseline: 7.8641x; 1.1478x over previous
//
#include <hip/hip_runtime.h>
#include <hip/hip_bf16.h>

// Motion-detection Gauss-LIF SNN:
//   K01 (fused, heterogeneous blocks):
//     blocks [0,512):    conv(16x9x9) via MFMA bf16 16x16x32 + LIF1 scan ->
//                        Z1 [800][65536] bf16 0/1 in k'-order.
//                        x = xh+xm (2 limbs), taps kh+kl; terms hh+mh+hl.
//                        (dropped kh*xl ~ 2^-18 <= already-dropped kl*xm ~ 2^-17)
//     blocks [512,6912): w1 -> bf16 hi/lo split, columns permuted to k'.
//     Independent outputs; fusion hides the split under the conv's slack.
//   K2: G2 = Z1 @ (wh+wl)^T MFMA GEMM, k-split partials, register prefetch.
//   K2b: reduce partials; K3: sequential LIF2+FC2+LIF3 scan.
// LIF recurrences __fmul_rn/__fadd_rn (no contract). Deterministic order.

typedef __attribute__((ext_vector_type(8))) short short8;
typedef __attribute__((ext_vector_type(4))) float f32x4;

#define B_   16
#define T_   50
#define HW_  4096
#define K1N  65536
#define M_   800
#define N2_  200
#define NP_  256
#define KSPL 64
#define BM2  128
#define BK2  32
#define KCH  (K1N / KSPL)  // 1024
#define MT2  7             // ceil(800/128)
#define SW   84            // conv tile stride (168B: 8B-aligned rows)
#define NCONV 512          // conv blocks
#define NPERM (200 * 32)   // permute blocks

static __device__ __forceinline__ short8 mk8(uint a, uint b, uint c, uint d){
  union { uint u[4]; short8 v; } x;
  x.u[0] = a; x.u[1] = b; x.u[2] = c; x.u[3] = d;
  return x.v;
}
static __device__ __forceinline__ uint fnl(uint a, uint b){ return (a >> 16) | (b << 16); }

// ---------------------------------------------------------------- conv helpers
template<bool WODD>
static __device__ __forceinline__ void rd5(const uint* p, int dw, uint e[5]){
  if (WODD){
    e[0] = p[dw];
    uint2 a = *(const uint2*)(p + dw + 1);
    uint2 b = *(const uint2*)(p + dw + 3);
    e[1] = a.x; e[2] = a.y; e[3] = b.x; e[4] = b.y;
  } else {
    uint2 a = *(const uint2*)(p + dw);
    uint2 b = *(const uint2*)(p + dw + 2);
    e[0] = a.x; e[1] = a.y; e[2] = b.x; e[3] = b.y;
    e[4] = p[dw + 4];
  }
}

template<bool WODD>
static __device__ __forceinline__ void conv_phase(const uint* T0, const uint* T1,
                                                  int bdw,
                                                  const short8 (&afh)[5],
                                                  const short8 (&afl)[5],
                                                  f32x4& acc0, f32x4& acc1){
  #pragma unroll
  for (int ks = 0; ks < 5; ++ks){
    const int dw = bdw + (SW / 2) * 2 * ks;   // +84 dwords per kstep (2 rows)
    uint h[5], m[5];
    rd5<WODD>(T0, dw, h);
    rd5<WODD>(T1, dw, m);
    short8 bh0 = mk8(h[0], h[1], h[2], h[3]);
    short8 bm0 = mk8(m[0], m[1], m[2], m[3]);
    acc0 = __builtin_amdgcn_mfma_f32_16x16x32_bf16(afh[ks], bh0, acc0, 0, 0, 0);
    acc0 = __builtin_amdgcn_mfma_f32_16x16x32_bf16(afh[ks], bm0, acc0, 0, 0, 0);
    acc0 = __builtin_amdgcn_mfma_f32_16x16x32_bf16(afl[ks], bh0, acc0, 0, 0, 0);
    short8 bh1 = mk8(fnl(h[0], h[1]), fnl(h[1], h[2]), fnl(h[2], h[3]), fnl(h[3], h[4]));
    short8 bm1 = mk8(fnl(m[0], m[1]), fnl(m[1], m[2]), fnl(m[2], m[3]), fnl(m[3], m[4]));
    acc1 = __builtin_amdgcn_mfma_f32_16x16x32_bf16(afh[ks], bh1, acc1, 0, 0, 0);
    acc1 = __builtin_amdgcn_mfma_f32_16x16x32_bf16(afh[ks], bm1, acc1, 0, 0, 0);
    acc1 = __builtin_amdgcn_mfma_f32_16x16x32_bf16(afl[ks], bh1, acc1, 0, 0, 0);
  }
}

// ---------------------------------------------------------------- K01: fused conv+LIF | w1 split
// smem layout (union):
//   conv: Ah[2560] | Alo[2560] | Tt[2][2][1008]      = 9152 ushorts
//   perm: lh[2048] | ll[2048]                        = 4096 ushorts
__global__ __launch_bounds__(256) void k01_fused(const float* __restrict__ x,
                                                 const float* __restrict__ kern,
                                                 const float* __restrict__ w1,
                                                 ushort* __restrict__ zout,
                                                 ushort* __restrict__ wh,
                                                 ushort* __restrict__ wl){
  __shared__ __align__(16) ushort smem[9152];
  const int bid = blockIdx.x;
  const int tid = threadIdx.x;

  if (bid >= NCONV){
    // ---------------- w1 split + k'-permute path ----------------
    ushort* lh = smem;
    ushort* ll = smem + 2048;
    const int bid2 = bid - NCONV;
    const int n = bid2 >> 5;
    const int strip = bid2 & 31;
    #pragma unroll
    for (int i = 0; i < 8; ++i){
      int lin = tid + 256 * i;               // ch*128 + p128
      int ch = lin >> 7, p128 = lin & 127;
      float v = w1[(size_t)n * K1N + ch * 4096 + strip * 128 + p128];
      int s = p128 >> 3, o = p128 & 7, q = ch >> 2, r = ch & 3;
      int kp = o * 256 + s * 16 + q * 4 + r;
      __hip_bfloat16 h = __float2bfloat16(v);
      float hf = __bfloat162float(h);
      __hip_bfloat16 lo = __float2bfloat16(v - hf);
      lh[kp] = *reinterpret_cast<ushort*>(&h);
      ll[kp] = *reinterpret_cast<ushort*>(&lo);
    }
    __syncthreads();
    const size_t ob = (size_t)n * K1N + strip * 2048;
    #pragma unroll
    for (int i = 0; i < 2; ++i){
      int j = (tid + 256 * i) * 4;
      *(ushort4*)(wh + ob + j) = make_ushort4(lh[j], lh[j+1], lh[j+2], lh[j+3]);
      *(ushort4*)(wl + ob + j) = make_ushort4(ll[j], ll[j+1], ll[j+2], ll[j+3]);
    }
    return;
  }

  // ---------------- conv + LIF1 path ----------------
  ushort* Ah  = smem;
  ushort* Alo = smem + 2560;
  ushort* Tt  = smem + 5120;                 // [buf][arr][1008]

  const int strip = bid & 31;
  const int b = bid >> 5;
  const int w = tid >> 6;
  const int l = tid & 63;
  const int q = l >> 4;
  const int s = l & 15;

  // ---- taps: kh + kl bf16 split, zero-padded to 10x16
  for (int slot = tid; slot < 16 * 160; slot += 256){
    int ch = slot / 160, kk = slot - ch * 160;
    int dy = kk >> 4, dx = kk & 15;
    float v = 0.f;
    if (dy < 9 && dx < 9) v = kern[ch * 81 + dy * 9 + dx];
    __hip_bfloat16 h = __float2bfloat16(v);
    float hf = __bfloat162float(h);
    __hip_bfloat16 lo = __float2bfloat16(v - hf);
    Ah[slot]  = *reinterpret_cast<ushort*>(&h);
    Alo[slot] = *reinterpret_cast<ushort*>(&lo);
  }

  // ---- staging geometry (threads 0..239)
  const bool sact = tid < 240;
  const int sr = tid / 20, sc4 = tid - sr * 20;
  const int r0 = 2 * strip - 4;
  const int imr = r0 + sr;
  const bool sin = sact && imr >= 0 && imr < 64 && sc4 >= 1 && sc4 <= 16;
  const float* xb = x + (size_t)b * (T_ * HW_);
  const float* xsrc = xb + (sin ? (imr * 64 + (sc4 - 1) * 4) : 0);

  // stage t=0 tile (2 limbs)
  {
    float4 f0 = make_float4(0.f, 0.f, 0.f, 0.f);
    if (sin) f0 = *(const float4*)(xsrc);
    if (sact){
      float vv[4] = {f0.x, f0.y, f0.z, f0.w};
      ushort sh[4], sm[4];
      #pragma unroll
      for (int ii = 0; ii < 4; ++ii){
        __hip_bfloat16 h = __float2bfloat16(vv[ii]);
        float t1 = vv[ii] - __bfloat162float(h);
        __hip_bfloat16 m = __float2bfloat16(t1);
        sh[ii] = *reinterpret_cast<ushort*>(&h);
        sm[ii] = *reinterpret_cast<ushort*>(&m);
      }
      int eb = sr * SW + sc4 * 4;
      *(ushort4*)(&Tt[0 * 1008 + eb]) = make_ushort4(sh[0], sh[1], sh[2], sh[3]);
      *(ushort4*)(&Tt[1 * 1008 + eb]) = make_ushort4(sm[0], sm[1], sm[2], sm[3]);
    }
  }
  __syncthreads();

  // ---- preload A-fragments
  short8 afh[5], afl[5];
  #pragma unroll
  for (int ks = 0; ks < 5; ++ks){
    afh[ks] = *(const short8*)(Ah + s * 160 + ks * 32 + q * 8);
    afl[ks] = *(const short8*)(Alo + s * 160 + ks * 32 + q * 8);
  }

  // window base in dwords: 42*p0 + 4*(s&7) + 4*(q&1) + w  (parity == w&1)
  const int p0 = (s >> 3) + (q >> 1);
  const int bdw = 42 * p0 + 4 * (s & 7) + 4 * (q & 1) + w;
  const bool wodd = (w & 1) != 0;

  float m1v[2][4];
  #pragma unroll
  for (int oi = 0; oi < 2; ++oi)
    #pragma unroll
    for (int r = 0; r < 4; ++r) m1v[oi][r] = 0.f;

  for (int t = 0; t < T_; ++t){
    __syncthreads();                           // Tt[t&1] ready
    // prefetch next-t pixels (consumed at end of this iteration)
    float4 nfx = make_float4(0.f, 0.f, 0.f, 0.f);
    if (t + 1 < T_ && sin) nfx = *(const float4*)(xsrc + (size_t)(t + 1) * HW_);

    const int bb = t & 1;
    const uint* T0 = (const uint*)&Tt[(bb * 2 + 0) * 1008];
    const uint* T1 = (const uint*)&Tt[(bb * 2 + 1) * 1008];
    f32x4 acc0 = (f32x4)(0.f), acc1 = (f32x4)(0.f);
    if (wodd) conv_phase<true >(T0, T1, bdw, afh, afl, acc0, acc1);
    else      conv_phase<false>(T0, T1, bdw, afh, afl, acc0, acc1);

    // ---- LIF1 + coalesced z store in k'-order
    const size_t zr = ((size_t)(t * B_ + b)) * K1N + strip * 2048 + s * 16 + q * 4;
    {
      ushort4 zv; ushort* zp = (ushort*)&zv;
      #pragma unroll
      for (int r = 0; r < 4; ++r){
        float m = m1v[0][r];
        float nm = (m > 1.0f) ? 0.0f : __fadd_rn(__fmul_rn(0.9f, m), acc0[r]);
        m1v[0][r] = nm;
        zp[r] = (nm > 1.0f) ? (ushort)0x3F80 : (ushort)0;
      }
      *(ushort4*)(zout + zr + (size_t)(2 * w) * 256) = zv;
    }
    {
      ushort4 zv; ushort* zp = (ushort*)&zv;
      #pragma unroll
      for (int r = 0; r < 4; ++r){
        float m = m1v[1][r];
        float nm = (m > 1.0f) ? 0.0f : __fadd_rn(__fmul_rn(0.9f, m), acc1[r]);
        m1v[1][r] = nm;
        zp[r] = (nm > 1.0f) ? (ushort)0x3F80 : (ushort)0;
      }
      *(ushort4*)(zout + zr + (size_t)(2 * w + 1) * 256) = zv;
    }

    // ---- stage next tile into the other buffer
    if (t + 1 < T_ && sact){
      float vv[4] = {nfx.x, nfx.y, nfx.z, nfx.w};
      ushort sh[4], sm[4];
      #pragma unroll
      for (int ii = 0; ii < 4; ++ii){
        __hip_bfloat16 h = __float2bfloat16(vv[ii]);
        float t1 = vv[ii] - __bfloat162float(h);
        __hip_bfloat16 m = __float2bfloat16(t1);
        sh[ii] = *reinterpret_cast<ushort*>(&h);
        sm[ii] = *reinterpret_cast<ushort*>(&m);
      }
      int eb = sr * SW + sc4 * 4;
      *(ushort4*)(&Tt[((bb ^ 1) * 2 + 0) * 1008 + eb]) = make_ushort4(sh[0], sh[1], sh[2], sh[3]);
      *(ushort4*)(&Tt[((bb ^ 1) * 2 + 1) * 1008 + eb]) = make_ushort4(sm[0], sm[1], sm[2], sm[3]);
    }
  }
}

// ---------------------------------------------------------------- K2 prefetch loader
static __device__ __forceinline__ void k2_load(const ushort* __restrict__ z,
                                               const ushort* __restrict__ wh,
                                               const ushort* __restrict__ wl,
                                               int m0, int kg, int tid,
                                               uint4 pa[2], uint4 pb[8]){
  #pragma unroll
  for (int i = 0; i < 2; ++i){
    int idx = tid + 256 * i;
    int row = idx >> 2, c16 = idx & 3;
    int m = m0 + row;
    pa[i] = make_uint4(0, 0, 0, 0);
    if (m < M_) pa[i] = *(const uint4*)(z + (size_t)m * K1N + kg + c16 * 8);
  }
  #pragma unroll
  for (int i = 0; i < 8; ++i){
    int idx = tid + 256 * i;
    int sel = idx >> 10;
    int r   = (idx >> 2) & 255;
    int c16 = idx & 3;
    const ushort* src = sel ? wl : wh;
    pb[i] = make_uint4(0, 0, 0, 0);
    if (r < N2_) pb[i] = *(const uint4*)(src + (size_t)r * K1N + kg + c16 * 8);
  }
}

// ---------------------------------------------------------------- K2: MFMA GEMM + prefetch
__global__ __launch_bounds__(256, 2) void k2_gemm(const ushort* __restrict__ z,
                                                  const ushort* __restrict__ wh,
                                                  const ushort* __restrict__ wl,
                                                  float* __restrict__ P){
  __shared__ __align__(16) ushort Al[128 * 40];
  __shared__ __align__(16) ushort Bw[512 * 40];

  const int bid = blockIdx.x;
  const int L = (bid & 7) * 56 + (bid >> 3);      // bijective: 448 = 8 * 56
  const int ks = L / MT2;
  const int mt = L % MT2;
  const int m0 = mt * BM2;
  const int k0 = ks * KCH;
  const int tid = threadIdx.x;
  const int w  = tid >> 6;
  const int l  = tid & 63;
  const int lr = l & 15;
  const int lq = l >> 4;

  f32x4 acc[8][4];
  #pragma unroll
  for (int mf = 0; mf < 8; ++mf)
    #pragma unroll
    for (int nf = 0; nf < 4; ++nf) acc[mf][nf] = (f32x4)(0.f);

  uint4 pa[2], pb[8];
  k2_load(z, wh, wl, m0, k0, tid, pa, pb);

  #pragma unroll 1
  for (int kc = 0; kc < KCH; kc += BK2){
    #pragma unroll
    for (int i = 0; i < 2; ++i){
      int idx = tid + 256 * i;
      int row = idx >> 2, c16 = idx & 3;
      *(uint4*)(Al + row * 40 + c16 * 8) = pa[i];
    }
    #pragma unroll
    for (int i = 0; i < 8; ++i){
      int idx = tid + 256 * i;
      int sel = idx >> 10;
      int r   = (idx >> 2) & 255;
      int c16 = idx & 3;
      *(uint4*)(Bw + (sel * 256 + r) * 40 + c16 * 8) = pb[i];
    }
    __syncthreads();

    if (kc + BK2 < KCH) k2_load(z, wh, wl, m0, k0 + kc + BK2, tid, pa, pb);

    short8 af[8], bh[4], bl[4];
    #pragma unroll
    for (int mf = 0; mf < 8; ++mf)
      af[mf] = *(const short8*)(Al + (mf * 16 + lr) * 40 + lq * 8);
    #pragma unroll
    for (int nf = 0; nf < 4; ++nf){
      bh[nf] = *(const short8*)(Bw + (w * 64 + nf * 16 + lr) * 40 + lq * 8);
      bl[nf] = *(const short8*)(Bw + (256 + w * 64 + nf * 16 + lr) * 40 + lq * 8);
    }
    #pragma unroll
    for (int mf = 0; mf < 8; ++mf)
      #pragma unroll
      for (int nf = 0; nf < 4; ++nf){
        acc[mf][nf] = __builtin_amdgcn_mfma_f32_16x16x32_bf16(af[mf], bh[nf], acc[mf][nf], 0, 0, 0);
        acc[mf][nf] = __builtin_amdgcn_mfma_f32_16x16x32_bf16(af[mf], bl[nf], acc[mf][nf], 0, 0, 0);
      }
    __syncthreads();
  }

  #pragma unroll
  for (int mf = 0; mf < 8; ++mf)
    #pragma unroll
    for (int nf = 0; nf < 4; ++nf)
      #pragma unroll
      for (int r = 0; r < 4; ++r){
        int m = m0 + mf * 16 + lq * 4 + r;
        int n = w * 64 + nf * 16 + lr;
        if (m < M_ && n < N2_)
          P[((size_t)ks * M_ + m) * N2_ + n] = acc[mf][nf][r];
      }
}

// ---------------------------------------------------------------- K2b: reduce k-splits
__global__ __launch_bounds__(256) void k2b_reduce(const float* __restrict__ P,
                                                  float* __restrict__ G2){
  int j = blockIdx.x * 256 + threadIdx.x;
  if (j >= M_ * N2_) return;
  float s = 0.f;
  #pragma unroll
  for (int ks = 0; ks < KSPL; ++ks) s += P[(size_t)ks * (M_ * N2_) + j];
  G2[j] = s;
}

// ---------------------------------------------------------------- K3: LIF2+FC2+LIF3 scan
__global__ __launch_bounds__(256) void k3_scan(const float* __restrict__ G2,
                                               const float* __restrict__ w2,
                                               float* __restrict__ out){
  const int b = blockIdx.x;
  const int tid = threadIdx.x;
  const float w = (tid < N2_) ? w2[tid] : 0.f;
  float m2 = 0.f, m3 = 0.f;
  __shared__ float part[4];

  float nxt = (tid < N2_) ? G2[(size_t)b * N2_ + tid] : 0.f;
  for (int t = 0; t < T_; ++t){
    float g2v = nxt;
    if (t < T_ - 1 && tid < N2_) nxt = G2[(size_t)((t + 1) * B_ + b) * N2_ + tid];
    float nm = (m2 > 1.0f) ? 0.f : __fadd_rn(__fmul_rn(0.9f, m2), g2v);
    m2 = nm;
    float s = (m2 > 1.0f) ? w : 0.f;
    #pragma unroll
    for (int off = 32; off > 0; off >>= 1) s += __shfl_down(s, off, 64);
    if ((tid & 63) == 0) part[tid >> 6] = s;
    __syncthreads();
    if (tid == 0){
      float g3 = (part[0] + part[1]) + (part[2] + part[3]);
      m3 = __fadd_rn(__fmul_rn(0.95f, m3), g3);
      out[b * T_ + t] = m3;
    }
    __syncthreads();
  }
}

// ---------------------------------------------------------------- host
extern "C" void kernel_launch(void* const* d_in, const int* in_sizes, int n_in,
                              void* d_out, int out_size, void* d_ws, size_t ws_size,
                              hipStream_t stream){
  const float* x    = (const float*)d_in[0];
  const float* kern = (const float*)d_in[1];
  const float* w1   = (const float*)d_in[2];
  const float* w2   = (const float*)d_in[3];
  float* out = (float*)d_out;

  char* p = (char*)d_ws;
  ushort* zb16 = (ushort*)p;                 p += (size_t)M_ * K1N * 2;
  ushort* wh   = (ushort*)p;                 p += (size_t)NP_ * K1N * 2;
  ushort* wl   = (ushort*)p;                 p += (size_t)NP_ * K1N * 2;
  float*  P    = (float*)p;                  p += (size_t)KSPL * M_ * N2_ * 4;
  float*  G2   = (float*)p;                  p += (size_t)M_ * N2_ * 4;

  size_t need = (size_t)(p - (char*)d_ws);
  if (ws_size < need) return;

  hipLaunchKernelGGL(k01_fused,  dim3(NCONV + NPERM), dim3(256), 0, stream,
                     x, kern, w1, zb16, wh, wl);
  hipLaunchKernelGGL(k2_gemm,    dim3(MT2 * KSPL), dim3(256), 0, stream, zb16, wh, wl, P);
  hipLaunchKernelGGL(k2b_reduce, dim3((M_ * N2_ + 255) / 256), dim3(256), 0, stream, P, G2);
  hipLaunchKernelGGL(k3_scan,    dim3(B_), dim3(256), 0, stream, G2, w2, out);
}

// Round 7
// 156.209 us; speedup vs baseline: 9.0143x; 1.1463x over previous
//
#include <hip/hip_runtime.h>
#include <hip/hip_bf16.h>

// Motion-detection Gauss-LIF SNN:
//   K01 (fused, heterogeneous blocks):
//     blocks [0,512):    conv(16x9x9) via MFMA bf16 16x16x32 + LIF1 ->
//                        Z1 [800][65536] int8 {0,1} in k'-order.
//     blocks [512,6912): w1 -> int8 fixed-point split, k'-permuted:
//                        w = A*2^-14 + B*2^-22, |A|<=65, B in [-128,127],
//                        |err| <= 2^-23 (exact borrow fix at B=+128).
//   K2: G2 = Z1 @ w1^T via TWO mfma_i32_16x16x64_i8 GEMMs (SA, SB), exact
//       i32 accumulation, combined fmaf(SA,2^-14, SB*2^-22). k-split partials.
//   K2b: reduce partials; K3: sequential LIF2+FC2+LIF3 scan.
// LIF recurrences __fmul_rn/__fadd_rn (no contract). Deterministic order.

typedef __attribute__((ext_vector_type(8))) short short8;
typedef __attribute__((ext_vector_type(4))) float f32x4;
typedef __attribute__((ext_vector_type(4))) int   i32x4;

#define B_   16
#define T_   50
#define HW_  4096
#define K1N  65536
#define M_   800
#define N2_  200
#define NP_  256
#define KSPL 64
#define BM2  64            // K2 m-tile
#define BK2  64            // K2 k-chunk (bytes = i8 elems)
#define KCH  (K1N / KSPL)  // 1024
#define MT2  13            // ceil(800/64)
#define SW   84            // conv tile stride
#define NCONV 512
#define NPERM (200 * 32)

static __device__ __forceinline__ short8 mk8(uint a, uint b, uint c, uint d){
  union { uint u[4]; short8 v; } x;
  x.u[0] = a; x.u[1] = b; x.u[2] = c; x.u[3] = d;
  return x.v;
}
static __device__ __forceinline__ uint fnl(uint a, uint b){ return (a >> 16) | (b << 16); }

// ---------------------------------------------------------------- conv helpers
template<bool WODD>
static __device__ __forceinline__ void rd5(const uint* p, int dw, uint e[5]){
  if (WODD){
    e[0] = p[dw];
    uint2 a = *(const uint2*)(p + dw + 1);
    uint2 b = *(const uint2*)(p + dw + 3);
    e[1] = a.x; e[2] = a.y; e[3] = b.x; e[4] = b.y;
  } else {
    uint2 a = *(const uint2*)(p + dw);
    uint2 b = *(const uint2*)(p + dw + 2);
    e[0] = a.x; e[1] = a.y; e[2] = b.x; e[3] = b.y;
    e[4] = p[dw + 4];
  }
}

template<bool WODD>
static __device__ __forceinline__ void conv_phase(const uint* T0, const uint* T1,
                                                  int bdw,
                                                  const short8 (&afh)[5],
                                                  const short8 (&afl)[5],
                                                  f32x4& acc0, f32x4& acc1){
  #pragma unroll
  for (int ks = 0; ks < 5; ++ks){
    const int dw = bdw + (SW / 2) * 2 * ks;
    uint h[5], m[5];
    rd5<WODD>(T0, dw, h);
    rd5<WODD>(T1, dw, m);
    short8 bh0 = mk8(h[0], h[1], h[2], h[3]);
    short8 bm0 = mk8(m[0], m[1], m[2], m[3]);
    acc0 = __builtin_amdgcn_mfma_f32_16x16x32_bf16(afh[ks], bh0, acc0, 0, 0, 0);
    acc0 = __builtin_amdgcn_mfma_f32_16x16x32_bf16(afh[ks], bm0, acc0, 0, 0, 0);
    acc0 = __builtin_amdgcn_mfma_f32_16x16x32_bf16(afl[ks], bh0, acc0, 0, 0, 0);
    short8 bh1 = mk8(fnl(h[0], h[1]), fnl(h[1], h[2]), fnl(h[2], h[3]), fnl(h[3], h[4]));
    short8 bm1 = mk8(fnl(m[0], m[1]), fnl(m[1], m[2]), fnl(m[2], m[3]), fnl(m[3], m[4]));
    acc1 = __builtin_amdgcn_mfma_f32_16x16x32_bf16(afh[ks], bh1, acc1, 0, 0, 0);
    acc1 = __builtin_amdgcn_mfma_f32_16x16x32_bf16(afh[ks], bm1, acc1, 0, 0, 0);
    acc1 = __builtin_amdgcn_mfma_f32_16x16x32_bf16(afl[ks], bh1, acc1, 0, 0, 0);
  }
}

// ---------------------------------------------------------------- K01: conv+LIF | w1 i8 split
__global__ __launch_bounds__(256) void k01_fused(const float* __restrict__ x,
                                                 const float* __restrict__ kern,
                                                 const float* __restrict__ w1,
                                                 unsigned char* __restrict__ zout,
                                                 char* __restrict__ wa,
                                                 char* __restrict__ wb){
  __shared__ __align__(16) ushort smem[9152];
  const int bid = blockIdx.x;
  const int tid = threadIdx.x;

  if (bid >= NCONV){
    // ---------------- w1 -> i8 (A,B) split + k'-permute ----------------
    char* la = (char*)smem;
    char* lb = la + 2048;
    const int bid2 = bid - NCONV;
    const int n = bid2 >> 5;
    const int strip = bid2 & 31;
    #pragma unroll
    for (int i = 0; i < 8; ++i){
      int lin = tid + 256 * i;               // ch*128 + p128
      int ch = lin >> 7, p128 = lin & 127;
      float v = w1[(size_t)n * K1N + ch * 4096 + strip * 128 + p128];
      int s = p128 >> 3, o = p128 & 7, q = ch >> 2, r = ch & 3;
      int kp = o * 256 + s * 16 + q * 4 + r;
      float af = rintf(v * 16384.f);         // |af| <= 64
      float rr = v - af * 0x1p-14f;          // exact (Sterbenz)
      float bf = rintf(rr * 0x1p22f);        // in [-128, 128]
      int A = (int)af, Bq = (int)bf;
      if (Bq == 128){ A += 1; Bq = -128; }   // exact borrow; |A| <= 65
      la[kp] = (char)A;
      lb[kp] = (char)Bq;
    }
    __syncthreads();
    const size_t ob = (size_t)n * K1N + strip * 2048;
    *(uint2*)(wa + ob + tid * 8) = *(const uint2*)(la + tid * 8);
    *(uint2*)(wb + ob + tid * 8) = *(const uint2*)(lb + tid * 8);
    return;
  }

  // ---------------- conv + LIF1 path ----------------
  ushort* Ah  = smem;
  ushort* Alo = smem + 2560;
  ushort* Tt  = smem + 5120;

  const int strip = bid & 31;
  const int b = bid >> 5;
  const int w = tid >> 6;
  const int l = tid & 63;
  const int q = l >> 4;
  const int s = l & 15;

  for (int slot = tid; slot < 16 * 160; slot += 256){
    int ch = slot / 160, kk = slot - ch * 160;
    int dy = kk >> 4, dx = kk & 15;
    float v = 0.f;
    if (dy < 9 && dx < 9) v = kern[ch * 81 + dy * 9 + dx];
    __hip_bfloat16 h = __float2bfloat16(v);
    float hf = __bfloat162float(h);
    __hip_bfloat16 lo = __float2bfloat16(v - hf);
    Ah[slot]  = *reinterpret_cast<ushort*>(&h);
    Alo[slot] = *reinterpret_cast<ushort*>(&lo);
  }

  const bool sact = tid < 240;
  const int sr = tid / 20, sc4 = tid - sr * 20;
  const int r0 = 2 * strip - 4;
  const int imr = r0 + sr;
  const bool sin = sact && imr >= 0 && imr < 64 && sc4 >= 1 && sc4 <= 16;
  const float* xb = x + (size_t)b * (T_ * HW_);
  const float* xsrc = xb + (sin ? (imr * 64 + (sc4 - 1) * 4) : 0);

  {
    float4 f0 = make_float4(0.f, 0.f, 0.f, 0.f);
    if (sin) f0 = *(const float4*)(xsrc);
    if (sact){
      float vv[4] = {f0.x, f0.y, f0.z, f0.w};
      ushort sh[4], sm[4];
      #pragma unroll
      for (int ii = 0; ii < 4; ++ii){
        __hip_bfloat16 h = __float2bfloat16(vv[ii]);
        float t1 = vv[ii] - __bfloat162float(h);
        __hip_bfloat16 m = __float2bfloat16(t1);
        sh[ii] = *reinterpret_cast<ushort*>(&h);
        sm[ii] = *reinterpret_cast<ushort*>(&m);
      }
      int eb = sr * SW + sc4 * 4;
      *(ushort4*)(&Tt[0 * 1008 + eb]) = make_ushort4(sh[0], sh[1], sh[2], sh[3]);
      *(ushort4*)(&Tt[1 * 1008 + eb]) = make_ushort4(sm[0], sm[1], sm[2], sm[3]);
    }
  }
  __syncthreads();

  short8 afh[5], afl[5];
  #pragma unroll
  for (int ks = 0; ks < 5; ++ks){
    afh[ks] = *(const short8*)(Ah + s * 160 + ks * 32 + q * 8);
    afl[ks] = *(const short8*)(Alo + s * 160 + ks * 32 + q * 8);
  }

  const int p0 = (s >> 3) + (q >> 1);
  const int bdw = 42 * p0 + 4 * (s & 7) + 4 * (q & 1) + w;
  const bool wodd = (w & 1) != 0;

  float m1v[2][4];
  #pragma unroll
  for (int oi = 0; oi < 2; ++oi)
    #pragma unroll
    for (int r = 0; r < 4; ++r) m1v[oi][r] = 0.f;

  for (int t = 0; t < T_; ++t){
    __syncthreads();
    float4 nfx = make_float4(0.f, 0.f, 0.f, 0.f);
    if (t + 1 < T_ && sin) nfx = *(const float4*)(xsrc + (size_t)(t + 1) * HW_);

    const int bb = t & 1;
    const uint* T0 = (const uint*)&Tt[(bb * 2 + 0) * 1008];
    const uint* T1 = (const uint*)&Tt[(bb * 2 + 1) * 1008];
    f32x4 acc0 = (f32x4)(0.f), acc1 = (f32x4)(0.f);
    if (wodd) conv_phase<true >(T0, T1, bdw, afh, afl, acc0, acc1);
    else      conv_phase<false>(T0, T1, bdw, afh, afl, acc0, acc1);

    // LIF1 + i8 spike store (4 bytes/lane, dense 256B per wave-offset)
    const size_t zr = ((size_t)(t * B_ + b)) * K1N + strip * 2048 + s * 16 + q * 4;
    {
      uint zw = 0;
      #pragma unroll
      for (int r = 0; r < 4; ++r){
        float m = m1v[0][r];
        float nm = (m > 1.0f) ? 0.0f : __fadd_rn(__fmul_rn(0.9f, m), acc0[r]);
        m1v[0][r] = nm;
        if (nm > 1.0f) zw |= (1u << (8 * r));
      }
      *(uint*)(zout + zr + (size_t)(2 * w) * 256) = zw;
    }
    {
      uint zw = 0;
      #pragma unroll
      for (int r = 0; r < 4; ++r){
        float m = m1v[1][r];
        float nm = (m > 1.0f) ? 0.0f : __fadd_rn(__fmul_rn(0.9f, m), acc1[r]);
        m1v[1][r] = nm;
        if (nm > 1.0f) zw |= (1u << (8 * r));
      }
      *(uint*)(zout + zr + (size_t)(2 * w + 1) * 256) = zw;
    }

    if (t + 1 < T_ && sact){
      float vv[4] = {nfx.x, nfx.y, nfx.z, nfx.w};
      ushort sh[4], sm[4];
      #pragma unroll
      for (int ii = 0; ii < 4; ++ii){
        __hip_bfloat16 h = __float2bfloat16(vv[ii]);
        float t1 = vv[ii] - __bfloat162float(h);
        __hip_bfloat16 m = __float2bfloat16(t1);
        sh[ii] = *reinterpret_cast<ushort*>(&h);
        sm[ii] = *reinterpret_cast<ushort*>(&m);
      }
      int eb = sr * SW + sc4 * 4;
      *(ushort4*)(&Tt[((bb ^ 1) * 2 + 0) * 1008 + eb]) = make_ushort4(sh[0], sh[1], sh[2], sh[3]);
      *(ushort4*)(&Tt[((bb ^ 1) * 2 + 1) * 1008 + eb]) = make_ushort4(sm[0], sm[1], sm[2], sm[3]);
    }
  }
}

// ---------------------------------------------------------------- K2 prefetch loader (i8)
static __device__ __forceinline__ void k2_load(const unsigned char* __restrict__ z,
                                               const char* __restrict__ wa,
                                               const char* __restrict__ wb,
                                               int m0, int kg, int tid,
                                               uint4& pa, uint4 pb[8]){
  {
    int row = tid >> 2, c16 = tid & 3;
    int m = m0 + row;
    pa = make_uint4(0, 0, 0, 0);
    if (m < M_) pa = *(const uint4*)(z + (size_t)m * K1N + kg + c16 * 16);
  }
  #pragma unroll
  for (int i = 0; i < 8; ++i){
    int idx = tid + 256 * i;
    int sel = idx >> 10;
    int r   = (idx >> 2) & 255;
    int c16 = idx & 3;
    const char* src = sel ? wb : wa;
    pb[i] = make_uint4(0, 0, 0, 0);
    if (r < N2_) pb[i] = *(const uint4*)(src + (size_t)r * K1N + kg + c16 * 16);
  }
}

// ---------------------------------------------------------------- K2: i8 MFMA GEMM
// grid 832 = m-tile(13 x 64) x k-split(64 x 1024); block 256 = 4 waves.
// XCD-chunked swizzle: 832 = 8 * 104; XCD x owns ks range [8x, 8x+8).
__global__ __launch_bounds__(256, 2) void k2_gemm(const unsigned char* __restrict__ z,
                                                  const char* __restrict__ wa,
                                                  const char* __restrict__ wb,
                                                  float* __restrict__ P){
  __shared__ __align__(16) unsigned char Al[64 * 80];    // A: 64 m x 64 k (+16 pad)
  __shared__ __align__(16) unsigned char Bw[512 * 80];   // wa rows 0-255, wb rows 256-511

  const int bid = blockIdx.x;
  const int L = (bid & 7) * 104 + (bid >> 3);     // bijective
  const int ks = L / MT2;
  const int mt = L % MT2;
  const int m0 = mt * BM2;
  const int k0 = ks * KCH;
  const int tid = threadIdx.x;
  const int w  = tid >> 6;
  const int l  = tid & 63;
  const int lr = l & 15;
  const int lq = l >> 4;

  const i32x4 zero4 = {0, 0, 0, 0};
  i32x4 accA[4][4], accB[4][4];
  #pragma unroll
  for (int mf = 0; mf < 4; ++mf)
    #pragma unroll
    for (int nf = 0; nf < 4; ++nf){ accA[mf][nf] = zero4; accB[mf][nf] = zero4; }

  uint4 pa, pb[8];
  k2_load(z, wa, wb, m0, k0, tid, pa, pb);

  #pragma unroll 1
  for (int kc = 0; kc < KCH; kc += BK2){
    // write prefetched tile to LDS
    {
      int row = tid >> 2, c16 = tid & 3;
      *(uint4*)(Al + row * 80 + c16 * 16) = pa;
    }
    #pragma unroll
    for (int i = 0; i < 8; ++i){
      int idx = tid + 256 * i;
      int sel = idx >> 10;
      int r   = (idx >> 2) & 255;
      int c16 = idx & 3;
      *(uint4*)(Bw + (sel * 256 + r) * 80 + c16 * 16) = pb[i];
    }
    __syncthreads();

    if (kc + BK2 < KCH) k2_load(z, wa, wb, m0, k0 + kc + BK2, tid, pa, pb);

    i32x4 af[4], ba[4], bbf[4];
    #pragma unroll
    for (int mf = 0; mf < 4; ++mf)
      af[mf] = *(const i32x4*)(Al + (mf * 16 + lr) * 80 + lq * 16);
    #pragma unroll
    for (int nf = 0; nf < 4; ++nf){
      ba[nf]  = *(const i32x4*)(Bw + (w * 64 + nf * 16 + lr) * 80 + lq * 16);
      bbf[nf] = *(const i32x4*)(Bw + (256 + w * 64 + nf * 16 + lr) * 80 + lq * 16);
    }
    #pragma unroll
    for (int mf = 0; mf < 4; ++mf)
      #pragma unroll
      for (int nf = 0; nf < 4; ++nf){
        accA[mf][nf] = __builtin_amdgcn_mfma_i32_16x16x64_i8(af[mf], ba[nf],  accA[mf][nf], 0, 0, 0);
        accB[mf][nf] = __builtin_amdgcn_mfma_i32_16x16x64_i8(af[mf], bbf[nf], accB[mf][nf], 0, 0, 0);
      }
    __syncthreads();
  }

  // epilogue: C row = lq*4+reg (m), col = lr (n); combine exact int sums
  #pragma unroll
  for (int mf = 0; mf < 4; ++mf)
    #pragma unroll
    for (int nf = 0; nf < 4; ++nf)
      #pragma unroll
      for (int r = 0; r < 4; ++r){
        int m = m0 + mf * 16 + lq * 4 + r;
        int n = w * 64 + nf * 16 + lr;
        if (m < M_ && n < N2_)
          P[((size_t)ks * M_ + m) * N2_ + n] =
            fmaf((float)accA[mf][nf][r], 0x1p-14f, (float)accB[mf][nf][r] * 0x1p-22f);
      }
}

// ---------------------------------------------------------------- K2b: reduce k-splits
__global__ __launch_bounds__(256) void k2b_reduce(const float* __restrict__ P,
                                                  float* __restrict__ G2){
  int j = blockIdx.x * 256 + threadIdx.x;
  if (j >= M_ * N2_) return;
  float s = 0.f;
  #pragma unroll
  for (int ks = 0; ks < KSPL; ++ks) s += P[(size_t)ks * (M_ * N2_) + j];
  G2[j] = s;
}

// ---------------------------------------------------------------- K3: LIF2+FC2+LIF3 scan
__global__ __launch_bounds__(256) void k3_scan(const float* __restrict__ G2,
                                               const float* __restrict__ w2,
                                               float* __restrict__ out){
  const int b = blockIdx.x;
  const int tid = threadIdx.x;
  const float w = (tid < N2_) ? w2[tid] : 0.f;
  float m2 = 0.f, m3 = 0.f;
  __shared__ float part[4];

  float nxt = (tid < N2_) ? G2[(size_t)b * N2_ + tid] : 0.f;
  for (int t = 0; t < T_; ++t){
    float g2v = nxt;
    if (t < T_ - 1 && tid < N2_) nxt = G2[(size_t)((t + 1) * B_ + b) * N2_ + tid];
    float nm = (m2 > 1.0f) ? 0.f : __fadd_rn(__fmul_rn(0.9f, m2), g2v);
    m2 = nm;
    float s = (m2 > 1.0f) ? w : 0.f;
    #pragma unroll
    for (int off = 32; off > 0; off >>= 1) s += __shfl_down(s, off, 64);
    if ((tid & 63) == 0) part[tid >> 6] = s;
    __syncthreads();
    if (tid == 0){
      float g3 = (part[0] + part[1]) + (part[2] + part[3]);
      m3 = __fadd_rn(__fmul_rn(0.95f, m3), g3);
      out[b * T_ + t] = m3;
    }
    __syncthreads();
  }
}

// ---------------------------------------------------------------- host
extern "C" void kernel_launch(void* const* d_in, const int* in_sizes, int n_in,
                              void* d_out, int out_size, void* d_ws, size_t ws_size,
                              hipStream_t stream){
  const float* x    = (const float*)d_in[0];
  const float* kern = (const float*)d_in[1];
  const float* w1   = (const float*)d_in[2];
  const float* w2   = (const float*)d_in[3];
  float* out = (float*)d_out;

  char* p = (char*)d_ws;
  unsigned char* z8 = (unsigned char*)p;     p += (size_t)M_ * K1N;            // 52.4 MB
  char* wa = p;                              p += (size_t)NP_ * K1N;           // 16.8 MB
  char* wb = p;                              p += (size_t)NP_ * K1N;           // 16.8 MB
  float* P  = (float*)p;                     p += (size_t)KSPL * M_ * N2_ * 4; // 41.0 MB
  float* G2 = (float*)p;                     p += (size_t)M_ * N2_ * 4;        // 0.64 MB

  size_t need = (size_t)(p - (char*)d_ws);
  if (ws_size < need) return;

  hipLaunchKernelGGL(k01_fused,  dim3(NCONV + NPERM), dim3(256), 0, stream,
                     x, kern, w1, z8, wa, wb);
  hipLaunchKernelGGL(k2_gemm,    dim3(MT2 * KSPL), dim3(256), 0, stream, z8, wa, wb, P);
  hipLaunchKernelGGL(k2b_reduce, dim3((M_ * N2_ + 255) / 256), dim3(256), 0, stream, P, G2);
  hipLaunchKernelGGL(k3_scan,    dim3(B_), dim3(256), 0, stream, G2, w2, out);
}